// Round 6
// baseline (1093.541 us; speedup 1.0000x reference)
//
#include <hip/hip_runtime.h>
#include <hip/hip_bf16.h>

#define BB 2
#define PP 128
#define CC 8
#define EE 1024
#define HH 16
#define KVHH 4
#define DD 64
#define TT 1024
#define EKVV 256

typedef unsigned short u16;
typedef unsigned int u32;

__device__ __forceinline__ float b2f(u16 u) {
    u32 x = ((u32)u) << 16;
    return __uint_as_float(x);
}
__device__ __forceinline__ u16 f2b(float f) {
    u32 x = __float_as_uint(f);
    u32 r = (x + 0x7FFFu + ((x >> 16) & 1u)) >> 16;
    return (u16)r;
}

// ---------------------------------------------------------------------------
// GEMM, fp32 A and B: C[M,N] = A[M,K] @ B[K,N], fp32 accumulate.
// 64x64 tile, BK=16, 256 threads, 4x4 microtile. Cb!=null -> bf16 out.
// ---------------------------------------------------------------------------
__global__ __launch_bounds__(256) void gemm_ff(const float* __restrict__ A,
                                               const float* __restrict__ Bm,
                                               float* __restrict__ Cf,
                                               u16* __restrict__ Cb,
                                               int M, int N, int K) {
    __shared__ float As[16][68];
    __shared__ float Bs[16][68];
    int tid = threadIdx.x;
    int tx = tid & 15, ty = tid >> 4;
    int m0 = blockIdx.y * 64, n0 = blockIdx.x * 64;
    float acc[4][4];
#pragma unroll
    for (int r = 0; r < 4; r++)
#pragma unroll
        for (int c = 0; c < 4; c++) acc[r][c] = 0.f;

    int am = tid >> 2, ak = (tid & 3) << 2;
    int bk = tid >> 4, bn = (tid & 15) << 2;

    for (int k0 = 0; k0 < K; k0 += 16) {
        int row = m0 + am;
        float4 av;
        if (row < M) av = *reinterpret_cast<const float4*>(A + (size_t)row * K + k0 + ak);
        else av = make_float4(0.f, 0.f, 0.f, 0.f);
        As[ak + 0][am] = av.x;
        As[ak + 1][am] = av.y;
        As[ak + 2][am] = av.z;
        As[ak + 3][am] = av.w;
        float4 bv = *reinterpret_cast<const float4*>(Bm + (size_t)(k0 + bk) * N + n0 + bn);
        Bs[bk][bn + 0] = bv.x;
        Bs[bk][bn + 1] = bv.y;
        Bs[bk][bn + 2] = bv.z;
        Bs[bk][bn + 3] = bv.w;
        __syncthreads();
#pragma unroll
        for (int kk = 0; kk < 16; kk++) {
            float4 a4 = *reinterpret_cast<const float4*>(&As[kk][ty << 2]);
            float4 b4 = *reinterpret_cast<const float4*>(&Bs[kk][tx << 2]);
            acc[0][0] += a4.x * b4.x; acc[0][1] += a4.x * b4.y; acc[0][2] += a4.x * b4.z; acc[0][3] += a4.x * b4.w;
            acc[1][0] += a4.y * b4.x; acc[1][1] += a4.y * b4.y; acc[1][2] += a4.y * b4.z; acc[1][3] += a4.y * b4.w;
            acc[2][0] += a4.z * b4.x; acc[2][1] += a4.z * b4.y; acc[2][2] += a4.z * b4.z; acc[2][3] += a4.z * b4.w;
            acc[3][0] += a4.w * b4.x; acc[3][1] += a4.w * b4.y; acc[3][2] += a4.w * b4.z; acc[3][3] += a4.w * b4.w;
        }
        __syncthreads();
    }
#pragma unroll
    for (int r = 0; r < 4; r++) {
        int row = m0 + (ty << 2) + r;
        if (row < M) {
#pragma unroll
            for (int c = 0; c < 4; c++) {
                int col = n0 + (tx << 2) + c;
                if (Cb) Cb[(size_t)row * N + col] = f2b(acc[r][c]);
                else    Cf[(size_t)row * N + col] = acc[r][c];
            }
        }
    }
}

// ---------------------------------------------------------------------------
// GEMM, bf16 A x fp32 B -> fp32 out (final projection into fp32 d_out).
// ---------------------------------------------------------------------------
__global__ __launch_bounds__(256) void gemm_bf(const u16* __restrict__ A,
                                               const float* __restrict__ Bm,
                                               float* __restrict__ Cf,
                                               int M, int N, int K) {
    __shared__ float As[16][68];
    __shared__ float Bs[16][68];
    int tid = threadIdx.x;
    int tx = tid & 15, ty = tid >> 4;
    int m0 = blockIdx.y * 64, n0 = blockIdx.x * 64;
    float acc[4][4];
#pragma unroll
    for (int r = 0; r < 4; r++)
#pragma unroll
        for (int c = 0; c < 4; c++) acc[r][c] = 0.f;

    int am = tid >> 2, ak = (tid & 3) << 2;
    int bk = tid >> 4, bn = (tid & 15) << 2;

    for (int k0 = 0; k0 < K; k0 += 16) {
        int row = m0 + am;
        ushort4 av;
        if (row < M) av = *reinterpret_cast<const ushort4*>(A + (size_t)row * K + k0 + ak);
        else av = make_ushort4(0, 0, 0, 0);
        As[ak + 0][am] = b2f(av.x);
        As[ak + 1][am] = b2f(av.y);
        As[ak + 2][am] = b2f(av.z);
        As[ak + 3][am] = b2f(av.w);
        float4 bv = *reinterpret_cast<const float4*>(Bm + (size_t)(k0 + bk) * N + n0 + bn);
        Bs[bk][bn + 0] = bv.x;
        Bs[bk][bn + 1] = bv.y;
        Bs[bk][bn + 2] = bv.z;
        Bs[bk][bn + 3] = bv.w;
        __syncthreads();
#pragma unroll
        for (int kk = 0; kk < 16; kk++) {
            float4 a4 = *reinterpret_cast<const float4*>(&As[kk][ty << 2]);
            float4 b4 = *reinterpret_cast<const float4*>(&Bs[kk][tx << 2]);
            acc[0][0] += a4.x * b4.x; acc[0][1] += a4.x * b4.y; acc[0][2] += a4.x * b4.z; acc[0][3] += a4.x * b4.w;
            acc[1][0] += a4.y * b4.x; acc[1][1] += a4.y * b4.y; acc[1][2] += a4.y * b4.z; acc[1][3] += a4.y * b4.w;
            acc[2][0] += a4.z * b4.x; acc[2][1] += a4.z * b4.y; acc[2][2] += a4.z * b4.z; acc[2][3] += a4.z * b4.w;
            acc[3][0] += a4.w * b4.x; acc[3][1] += a4.w * b4.y; acc[3][2] += a4.w * b4.z; acc[3][3] += a4.w * b4.w;
        }
        __syncthreads();
    }
#pragma unroll
    for (int r = 0; r < 4; r++) {
        int row = m0 + (ty << 2) + r;
        if (row < M) {
#pragma unroll
            for (int c = 0; c < 4; c++) {
                int col = n0 + (tx << 2) + c;
                Cf[(size_t)row * N + col] = acc[r][c];
            }
        }
    }
}

// ---------------------------------------------------------------------------
// gk transpose: gkt[b][kvh][d][s] = kv[b*T+s][kvh*64+d]  (bf16 in/out)
// ---------------------------------------------------------------------------
__global__ __launch_bounds__(256) void k_gkt(const u16* __restrict__ kvb,
                                             u16* __restrict__ gkt) {
    int k = blockIdx.x * 256 + threadIdx.x;  // < 524288
    int s = k & 1023, d = (k >> 10) & 63, kvh = (k >> 16) & 3, b = k >> 18;
    gkt[k] = kvb[((size_t)(b * TT + s)) * (2 * EKVV) + kvh * 64 + d];
}

// ---------------------------------------------------------------------------
// Flash attention, one wave per query row t, with rel-shifted time and
// channel scores computed in-kernel via the inverse gather:
//   tshift[t][ps]: g=(t+1)*128+ps; a=g/1025, r=g%1025; r==0 -> 0,
//   else f=1024a+r-1, t'=f>>7, p'=f&127, val=(q[t']+tb).tk[p']
//   cshift[t][c] = (q[t]+cb).ck[7-|t%8-c|]
// Online softmax over s < (pi+1)*8 with window mask on the global term.
// bias is fp32. Writes bf16 A2 in (b*T+t, h*64+d) layout.
// ---------------------------------------------------------------------------
__global__ __launch_bounds__(256) void k_flash(const u16* __restrict__ qb,
                                               const u16* __restrict__ gkt,
                                               const u16* __restrict__ kvb,
                                               const float* __restrict__ tkb,
                                               const float* __restrict__ ckb,
                                               const float* __restrict__ bias,
                                               u16* __restrict__ A2) {
    int lane = threadIdx.x & 63;
    int wave = threadIdx.x >> 6;
    int i = blockIdx.x * 4 + wave;  // query row t
    int h = blockIdx.y, b = blockIdx.z;
    int kvh = h >> 2;

    __shared__ float qgs[4][64];
    __shared__ float tshs[4][128];
    __shared__ float cshs[4][8];

    float qv = b2f(qb[((size_t)(b * TT + i)) * EE + h * 64 + lane]);
    qgs[wave][lane] = qv + bias[kvh * 64 + lane];

    // time-shift scores: 2 per lane (ps = lane, lane+64)
#pragma unroll
    for (int rep = 0; rep < 2; rep++) {
        int ps = lane + (rep << 6);
        int g = i * PP + ps + PP;
        int a = g / 1025;
        int r = g - a * 1025;
        float val = 0.f;
        if (r != 0) {
            int f = (a << 10) + r - 1;
            int tp = f >> 7, pp = f & 127;
            const u16* q2 = qb + ((size_t)(b * TT + tp)) * EE + h * 64;
            const float* tb = bias + EKVV + kvh * 64;
            const float* tkr = tkb + pp * EKVV + kvh * 64;
            float acc = 0.f;
#pragma unroll 8
            for (int d = 0; d < 64; d++)
                acc += (b2f(q2[d]) + tb[d]) * tkr[d];
            val = acc;
        }
        tshs[wave][ps] = val;
    }
    // chan scores: lanes 0..7 (c = lane)
    if (lane < 8) {
        int df = (i & 7) - lane;
        if (df < 0) df = -df;
        const float* ckr = ckb + (7 - df) * EKVV + kvh * 64;
        const float* cb = bias + 2 * EKVV + kvh * 64;
        const u16* q1 = qb + ((size_t)(b * TT + i)) * EE + h * 64;
        float acc = 0.f;
#pragma unroll 8
        for (int d = 0; d < 64; d++)
            acc += (b2f(q1[d]) + cb[d]) * ckr[d];
        cshs[wave][lane] = acc;
    }
    __syncthreads();

    const float* qrow = qgs[wave];
    const float* tsrow = tshs[wave];
    const float* csrow = cshs[wave];
    int pi = i >> 3;
    int limit = (pi + 1) << 3;
    bool lastrow = (pi == PP - 1);
    const float BIG = 1.0e30f;
    float m = -BIG, l = 0.f, acc = 0.f;
    const u16* gbase = gkt + ((size_t)(b * KVHH + kvh)) * DD * TT;
    const u16* vbase = kvb + ((size_t)b * TT) * (2 * EKVV) + EKVV + kvh * 64;

    for (int s0 = 0; s0 < limit; s0 += 64) {
        int s = s0 + lane;
        int ps = s >> 3;
        float dot = 0.f;
        int chunkHi = (s0 + 63) >> 3;
        bool anywin = lastrow || (chunkHi >= pi - 10);
        if (anywin) {
            const u16* gp = gbase + s0 + lane;
#pragma unroll 8
            for (int dd = 0; dd < 64; dd++) dot += qrow[dd] * b2f(gp[dd << 10]);
            bool win = lastrow || (pi - ps <= 10);  // ps<=pi for valid lanes
            if (!win) dot = 0.f;
        }
        float sc;
        if (s < limit) sc = (dot + tsrow[ps] + csrow[s & 7]) * 0.125f;
        else sc = -BIG;
        float cmax = sc;
#pragma unroll
        for (int off = 32; off; off >>= 1) cmax = fmaxf(cmax, __shfl_xor(cmax, off));
        float mnew = fmaxf(m, cmax);
        float alpha = __expf(m - mnew);
        float w = __expf(sc - mnew);
        float wsum = w;
#pragma unroll
        for (int off = 32; off; off >>= 1) wsum += __shfl_xor(wsum, off);
        l = l * alpha + wsum;
        acc *= alpha;
        int jmax = min(64, limit - s0);
        const u16* vp = vbase + (size_t)s0 * (2 * EKVV) + lane;
        for (int jj = 0; jj < jmax; jj++) {
            float wj = __shfl(w, jj);
            acc += wj * b2f(vp[(size_t)jj * (2 * EKVV)]);
        }
        m = mnew;
    }
    A2[((size_t)(b * TT + i)) * EE + h * 64 + lane] = f2b(acc / l);
}

extern "C" void kernel_launch(void* const* d_in, const int* in_sizes, int n_in,
                              void* d_out, int out_size, void* d_ws, size_t ws_size,
                              hipStream_t stream) {
    // fp32 inputs, fp32 output (reference dtypes)
    const float* hidden = (const float*)d_in[0];
    const float* pos    = (const float*)d_in[1];
    const float* chan   = (const float*)d_in[2];
    const float* Wq     = (const float*)d_in[3];
    const float* Wkv    = (const float*)d_in[4];
    const float* Wpos   = (const float*)d_in[5];
    const float* Wchan  = (const float*)d_in[6];
    const float* Wproj  = (const float*)d_in[7];
    const float* bias   = (const float*)d_in[8];

    // workspace carve: 11,163,648 bytes total
    u16* qb    = (u16*)d_ws;               // 2,097,152 u16 (4 MB)
    u16* kvb   = qb + 2097152;             // 1,048,576 u16 (2 MB)
    u16* gkt   = kvb + 1048576;            //   524,288 u16 (1 MB)
    float* tkb = (float*)(gkt + 524288);   //    32,768 f32 (128 KB)
    float* ckb = tkb + 32768;              //     2,048 f32 (8 KB)
    u16* A2    = (u16*)(ckb + 2048);       // 2,097,152 u16 (4 MB)

    dim3 blk(256);
    // projections (q, kv -> bf16 ws; tk, ck -> fp32 ws)
    gemm_ff<<<dim3(16, 32), blk, 0, stream>>>(hidden, Wq,   nullptr, qb,  2048, 1024, 1024);
    gemm_ff<<<dim3(8,  32), blk, 0, stream>>>(hidden, Wkv,  nullptr, kvb, 2048, 512,  1024);
    gemm_ff<<<dim3(4,  2),  blk, 0, stream>>>(pos,    Wpos, tkb, nullptr, 128,  256,  1024);
    gemm_ff<<<dim3(4,  1),  blk, 0, stream>>>(chan,   Wchan,ckb, nullptr, 8,    256,  1024);
    // gk transpose
    k_gkt<<<2048, 256, 0, stream>>>(kvb, gkt);
    // flash attention with fused rel-shift score computation -> A2 (bf16)
    k_flash<<<dim3(256, 16, 2), 256, 0, stream>>>(qb, gkt, kvb, tkb, ckb, bias, A2);
    // output projection -> fp32 d_out
    gemm_bf<<<dim3(16, 32), blk, 0, stream>>>(A2, Wproj, (float*)d_out, 2048, 1024, 1024);
}

// Round 7
// 676.889 us; speedup vs baseline: 1.6155x; 1.6155x over previous
//
#include <hip/hip_runtime.h>
#include <hip/hip_bf16.h>

#define BB 2
#define PP 128
#define CC 8
#define EE 1024
#define HH 16
#define KVHH 4
#define DD 64
#define TT 1024
#define EKVV 256

typedef unsigned short u16;
typedef unsigned int u32;

__device__ __forceinline__ float b2f(u16 u) {
    u32 x = ((u32)u) << 16;
    return __uint_as_float(x);
}
__device__ __forceinline__ u16 f2b(float f) {
    u32 x = __float_as_uint(f);
    u32 r = (x + 0x7FFFu + ((x >> 16) & 1u)) >> 16;
    return (u16)r;
}

// ---------------------------------------------------------------------------
// GEMM, fp32 A and B: C[M,N] = A[M,K] @ B[K,N], fp32 accumulate.
// 64x64 tile, BK=16, 256 threads, 4x4 microtile. Cb!=null -> bf16 out.
// ---------------------------------------------------------------------------
__global__ __launch_bounds__(256) void gemm_ff(const float* __restrict__ A,
                                               const float* __restrict__ Bm,
                                               float* __restrict__ Cf,
                                               u16* __restrict__ Cb,
                                               int M, int N, int K) {
    __shared__ float As[16][68];
    __shared__ float Bs[16][68];
    int tid = threadIdx.x;
    int tx = tid & 15, ty = tid >> 4;
    int m0 = blockIdx.y * 64, n0 = blockIdx.x * 64;
    float acc[4][4];
#pragma unroll
    for (int r = 0; r < 4; r++)
#pragma unroll
        for (int c = 0; c < 4; c++) acc[r][c] = 0.f;

    int am = tid >> 2, ak = (tid & 3) << 2;
    int bk = tid >> 4, bn = (tid & 15) << 2;

    for (int k0 = 0; k0 < K; k0 += 16) {
        int row = m0 + am;
        float4 av;
        if (row < M) av = *reinterpret_cast<const float4*>(A + (size_t)row * K + k0 + ak);
        else av = make_float4(0.f, 0.f, 0.f, 0.f);
        As[ak + 0][am] = av.x;
        As[ak + 1][am] = av.y;
        As[ak + 2][am] = av.z;
        As[ak + 3][am] = av.w;
        float4 bv = *reinterpret_cast<const float4*>(Bm + (size_t)(k0 + bk) * N + n0 + bn);
        Bs[bk][bn + 0] = bv.x;
        Bs[bk][bn + 1] = bv.y;
        Bs[bk][bn + 2] = bv.z;
        Bs[bk][bn + 3] = bv.w;
        __syncthreads();
#pragma unroll
        for (int kk = 0; kk < 16; kk++) {
            float4 a4 = *reinterpret_cast<const float4*>(&As[kk][ty << 2]);
            float4 b4 = *reinterpret_cast<const float4*>(&Bs[kk][tx << 2]);
            acc[0][0] += a4.x * b4.x; acc[0][1] += a4.x * b4.y; acc[0][2] += a4.x * b4.z; acc[0][3] += a4.x * b4.w;
            acc[1][0] += a4.y * b4.x; acc[1][1] += a4.y * b4.y; acc[1][2] += a4.y * b4.z; acc[1][3] += a4.y * b4.w;
            acc[2][0] += a4.z * b4.x; acc[2][1] += a4.z * b4.y; acc[2][2] += a4.z * b4.z; acc[2][3] += a4.z * b4.w;
            acc[3][0] += a4.w * b4.x; acc[3][1] += a4.w * b4.y; acc[3][2] += a4.w * b4.z; acc[3][3] += a4.w * b4.w;
        }
        __syncthreads();
    }
#pragma unroll
    for (int r = 0; r < 4; r++) {
        int row = m0 + (ty << 2) + r;
        if (row < M) {
#pragma unroll
            for (int c = 0; c < 4; c++) {
                int col = n0 + (tx << 2) + c;
                if (Cb) Cb[(size_t)row * N + col] = f2b(acc[r][c]);
                else    Cf[(size_t)row * N + col] = acc[r][c];
            }
        }
    }
}

// ---------------------------------------------------------------------------
// GEMM, bf16 A x fp32 B -> fp32 out (final projection into fp32 d_out).
// ---------------------------------------------------------------------------
__global__ __launch_bounds__(256) void gemm_bf(const u16* __restrict__ A,
                                               const float* __restrict__ Bm,
                                               float* __restrict__ Cf,
                                               int M, int N, int K) {
    __shared__ float As[16][68];
    __shared__ float Bs[16][68];
    int tid = threadIdx.x;
    int tx = tid & 15, ty = tid >> 4;
    int m0 = blockIdx.y * 64, n0 = blockIdx.x * 64;
    float acc[4][4];
#pragma unroll
    for (int r = 0; r < 4; r++)
#pragma unroll
        for (int c = 0; c < 4; c++) acc[r][c] = 0.f;

    int am = tid >> 2, ak = (tid & 3) << 2;
    int bk = tid >> 4, bn = (tid & 15) << 2;

    for (int k0 = 0; k0 < K; k0 += 16) {
        int row = m0 + am;
        ushort4 av;
        if (row < M) av = *reinterpret_cast<const ushort4*>(A + (size_t)row * K + k0 + ak);
        else av = make_ushort4(0, 0, 0, 0);
        As[ak + 0][am] = b2f(av.x);
        As[ak + 1][am] = b2f(av.y);
        As[ak + 2][am] = b2f(av.z);
        As[ak + 3][am] = b2f(av.w);
        float4 bv = *reinterpret_cast<const float4*>(Bm + (size_t)(k0 + bk) * N + n0 + bn);
        Bs[bk][bn + 0] = bv.x;
        Bs[bk][bn + 1] = bv.y;
        Bs[bk][bn + 2] = bv.z;
        Bs[bk][bn + 3] = bv.w;
        __syncthreads();
#pragma unroll
        for (int kk = 0; kk < 16; kk++) {
            float4 a4 = *reinterpret_cast<const float4*>(&As[kk][ty << 2]);
            float4 b4 = *reinterpret_cast<const float4*>(&Bs[kk][tx << 2]);
            acc[0][0] += a4.x * b4.x; acc[0][1] += a4.x * b4.y; acc[0][2] += a4.x * b4.z; acc[0][3] += a4.x * b4.w;
            acc[1][0] += a4.y * b4.x; acc[1][1] += a4.y * b4.y; acc[1][2] += a4.y * b4.z; acc[1][3] += a4.y * b4.w;
            acc[2][0] += a4.z * b4.x; acc[2][1] += a4.z * b4.y; acc[2][2] += a4.z * b4.z; acc[2][3] += a4.z * b4.w;
            acc[3][0] += a4.w * b4.x; acc[3][1] += a4.w * b4.y; acc[3][2] += a4.w * b4.z; acc[3][3] += a4.w * b4.w;
        }
        __syncthreads();
    }
#pragma unroll
    for (int r = 0; r < 4; r++) {
        int row = m0 + (ty << 2) + r;
        if (row < M) {
#pragma unroll
            for (int c = 0; c < 4; c++) {
                int col = n0 + (tx << 2) + c;
                Cf[(size_t)row * N + col] = acc[r][c];
            }
        }
    }
}

// ---------------------------------------------------------------------------
// k_ta: raw time_att GEMM with fused rel-shift scatter (row-contiguous).
// Per (b,h): raw[t',p'] = (q[t']+tb) . tk[p'].  Shifted flat index =
// t'*128 + t'/8 + 1 - 128 + p'  (guard >= 0); zero slots at 1025*a-128.
// Grid (16 t-tiles, 16 h, 2 b), 256 threads. Output tsb bf16 [b,h,1024,128].
// ---------------------------------------------------------------------------
__global__ __launch_bounds__(256) void k_ta(const u16* __restrict__ qb,
                                            const float* __restrict__ tkb,
                                            const float* __restrict__ bias,
                                            u16* __restrict__ tsb) {
    __shared__ float qs[64][65];
    __shared__ float tks[128][65];
    int tid = threadIdx.x;
    int t0 = blockIdx.x * 64;
    int h = blockIdx.y, b = blockIdx.z;
    int kvh = h >> 2;

#pragma unroll
    for (int it = 0; it < 16; it++) {
        int idx = tid + it * 256;         // 4096 = 64x64
        int row = idx >> 6, d = idx & 63;
        qs[row][d] = b2f(qb[((size_t)(b * TT + t0 + row)) * EE + h * 64 + d])
                   + bias[EKVV + kvh * 64 + d];
    }
#pragma unroll
    for (int it = 0; it < 32; it++) {
        int idx = tid + it * 256;         // 8192 = 128x64
        int p = idx >> 6, d = idx & 63;
        tks[p][d] = tkb[p * EKVV + kvh * 64 + d];
    }
    __syncthreads();

    int tx = tid & 31, ty = tid >> 5;     // p = tx + 32*j, rows = ty*8..+8
    float acc[8][4];
#pragma unroll
    for (int i = 0; i < 8; i++)
#pragma unroll
        for (int j = 0; j < 4; j++) acc[i][j] = 0.f;

    for (int d = 0; d < 64; d++) {
        float tv[4];
#pragma unroll
        for (int j = 0; j < 4; j++) tv[j] = tks[tx + 32 * j][d];
#pragma unroll
        for (int i = 0; i < 8; i++) {
            float qv = qs[ty * 8 + i][d];
#pragma unroll
            for (int j = 0; j < 4; j++) acc[i][j] += qv * tv[j];
        }
    }

    size_t basebh = ((size_t)(b * HH + h)) * (TT * PP);
#pragma unroll
    for (int i = 0; i < 8; i++) {
        int tp = t0 + ty * 8 + i;
        int gbase = tp * PP + (tp >> 3) + 1 - PP;
#pragma unroll
        for (int j = 0; j < 4; j++) {
            int ppx = tx + 32 * j;
            int o = gbase + ppx;
            if (o >= 0) tsb[basebh + o] = f2b(acc[i][j]);
        }
    }
    if (tid < 64) {
        int tp = t0 + tid;
        if (tp >= 1 && tp < 128) tsb[basebh + 1025 * tp - PP] = 0;  // bf16 zero
    }
}

// ---------------------------------------------------------------------------
// k_att2: block attention. One block per (pi, h, b); 8 query rows/block.
// w[8][1024] scores in LDS; chunked K/V staging (bf16) in LDS; two-pass
// softmax; PV with 2 output pairs/thread. Writes bf16 A2.
// ---------------------------------------------------------------------------
__global__ __launch_bounds__(256) void k_att2(const u16* __restrict__ qb,
                                              const u16* __restrict__ kvb,
                                              const u16* __restrict__ tsb,
                                              const float* __restrict__ ckb,
                                              const float* __restrict__ bias,
                                              u16* __restrict__ A2) {
    __shared__ float w[8][1024];      // 32768 B
    __shared__ u16 stage[64][130];    // 16640 B (K then V, d-major)
    __shared__ float qg[8][64];       // 2048 B
    __shared__ float ts8[8][128];     // 4096 B
    __shared__ float cs8[8][8];       // 256 B
    __shared__ float red[256];        // 1024 B
    __shared__ float rowm[8], rowl[8];

    int tid = threadIdx.x;
    int pi = blockIdx.x, h = blockIdx.y, b = blockIdx.z;
    int kvh = h >> 2;
    int t0 = pi << 3;
    int limit = (pi + 1) << 3;
    bool lastrow = (pi == PP - 1);
    int winLo = lastrow ? 0 : (pi - 10) << 3;
    if (winLo < 0) winLo = 0;

    // ---- load qg (q + gb) ----
#pragma unroll
    for (int it = 0; it < 2; it++) {
        int idx = tid + it * 256;     // 512 = 8x64
        int r = idx >> 6, d = idx & 63;
        qg[r][d] = b2f(qb[((size_t)(b * TT + t0 + r)) * EE + h * 64 + d])
                 + bias[kvh * 64 + d];
    }
    // ---- load ts8 from shifted time scores ----
#pragma unroll
    for (int it = 0; it < 4; it++) {
        int idx = tid + it * 256;     // 1024 = 8x128
        int r = idx >> 7, ps = idx & 127;
        ts8[r][ps] = b2f(tsb[((size_t)(b * HH + h)) * (TT * PP) + (size_t)(t0 + r) * PP + ps]);
    }
    // ---- chan scores: 64 dots (r, c) ----
    if (tid < 64) {
        int r = tid >> 3, c = tid & 7;
        int df = r - c; if (df < 0) df = -df;
        const float* ckr = ckb + (7 - df) * EKVV + kvh * 64;
        const float* cb = bias + 2 * EKVV + kvh * 64;
        const u16* q1 = qb + ((size_t)(b * TT + t0 + r)) * EE + h * 64;
        float acc = 0.f;
#pragma unroll 8
        for (int d = 0; d < 64; d++) acc += (b2f(q1[d]) + cb[d]) * ckr[d];
        cs8[r][c] = acc;
    }
    __syncthreads();

    // ---- init scores with (ts + cs)/8 ----
    for (int r = 0; r < 8; r++)
        for (int s = tid; s < limit; s += 256)
            w[r][s] = (ts8[r][s >> 3] + cs8[r][s & 7]) * 0.125f;
    __syncthreads();

    // ---- windowed global QK: chunks of 128 ----
    for (int c0 = winLo & ~127; c0 < limit; c0 += 128) {
        int nr = min(128, limit - c0);
        // stage K rows [c0, c0+nr) -> stage[d][s] bf16
        for (int idx = tid; idx < nr * 8; idx += 256) {
            int s = idx >> 3, part = idx & 7;
            uint4 u = *reinterpret_cast<const uint4*>(
                kvb + ((size_t)(b * TT + c0 + s)) * (2 * EKVV) + kvh * 64 + part * 8);
            int dbase = part * 8;
            stage[dbase + 0][s] = (u16)(u.x & 0xffff);
            stage[dbase + 1][s] = (u16)(u.x >> 16);
            stage[dbase + 2][s] = (u16)(u.y & 0xffff);
            stage[dbase + 3][s] = (u16)(u.y >> 16);
            stage[dbase + 4][s] = (u16)(u.z & 0xffff);
            stage[dbase + 5][s] = (u16)(u.z >> 16);
            stage[dbase + 6][s] = (u16)(u.w & 0xffff);
            stage[dbase + 7][s] = (u16)(u.w >> 16);
        }
        __syncthreads();
        int sLo = c0 > winLo ? c0 : winLo;
        int cnt = c0 + nr - sLo;
        for (int idx = tid; idx < 8 * cnt; idx += 256) {
            int r = idx / cnt;
            int s = sLo + (idx - r * cnt);
            int sc = s - c0;
            float dot = 0.f;
#pragma unroll 8
            for (int d = 0; d < 64; d++) dot += qg[r][d] * b2f(stage[d][sc]);
            w[r][s] += dot * 0.125f;
        }
        __syncthreads();
    }

    // ---- softmax (two-pass, 32 threads per row) ----
    {
        int g = tid >> 5, l32 = tid & 31;
        float pm = -1.0e30f;
        for (int s = l32; s < limit; s += 32) pm = fmaxf(pm, w[g][s]);
        red[tid] = pm;
        __syncthreads();
        if (tid < 8) {
            float mm = -1.0e30f;
            for (int i = 0; i < 32; i++) mm = fmaxf(mm, red[tid * 32 + i]);
            rowm[tid] = mm;
        }
        __syncthreads();
        float mr = rowm[g];
        float psum = 0.f;
        for (int s = l32; s < limit; s += 32) {
            float e = __expf(w[g][s] - mr);
            w[g][s] = e;
            psum += e;
        }
        red[tid] = psum;
        __syncthreads();
        if (tid < 8) {
            float ss = 0.f;
            for (int i = 0; i < 32; i++) ss += red[tid * 32 + i];
            rowl[tid] = ss;
        }
        __syncthreads();
    }

    // ---- PV: chunks of 128, 2 output pairs per thread ----
    int d = tid & 63;
    int r0 = tid >> 6, r1 = r0 + 4;
    float out0 = 0.f, out1 = 0.f;
    for (int c0 = 0; c0 < limit; c0 += 128) {
        int nr = min(128, limit - c0);
        __syncthreads();  // protect stage from previous use
        for (int idx = tid; idx < nr * 8; idx += 256) {
            int s = idx >> 3, part = idx & 7;
            uint4 u = *reinterpret_cast<const uint4*>(
                kvb + ((size_t)(b * TT + c0 + s)) * (2 * EKVV) + EKVV + kvh * 64 + part * 8);
            int dbase = part * 8;
            stage[dbase + 0][s] = (u16)(u.x & 0xffff);
            stage[dbase + 1][s] = (u16)(u.x >> 16);
            stage[dbase + 2][s] = (u16)(u.y & 0xffff);
            stage[dbase + 3][s] = (u16)(u.y >> 16);
            stage[dbase + 4][s] = (u16)(u.z & 0xffff);
            stage[dbase + 5][s] = (u16)(u.z >> 16);
            stage[dbase + 6][s] = (u16)(u.w & 0xffff);
            stage[dbase + 7][s] = (u16)(u.w >> 16);
        }
        __syncthreads();
        for (int s = 0; s < nr; s++) {
            float vv = b2f(stage[d][s]);
            out0 += w[r0][c0 + s] * vv;
            out1 += w[r1][c0 + s] * vv;
        }
    }
    A2[((size_t)(b * TT + t0 + r0)) * EE + h * 64 + d] = f2b(out0 / rowl[r0]);
    A2[((size_t)(b * TT + t0 + r1)) * EE + h * 64 + d] = f2b(out1 / rowl[r1]);
}

extern "C" void kernel_launch(void* const* d_in, const int* in_sizes, int n_in,
                              void* d_out, int out_size, void* d_ws, size_t ws_size,
                              hipStream_t stream) {
    const float* hidden = (const float*)d_in[0];
    const float* pos    = (const float*)d_in[1];
    const float* chan   = (const float*)d_in[2];
    const float* Wq     = (const float*)d_in[3];
    const float* Wkv    = (const float*)d_in[4];
    const float* Wpos   = (const float*)d_in[5];
    const float* Wchan  = (const float*)d_in[6];
    const float* Wproj  = (const float*)d_in[7];
    const float* bias   = (const float*)d_in[8];

    // workspace carve: ~18.3 MB total
    u16* qb    = (u16*)d_ws;               // 2,097,152 u16 (4 MB)
    u16* kvb   = qb + 2097152;             // 1,048,576 u16 (2 MB)
    u16* tsb   = kvb + 1048576;            // 4,194,304 u16 (8 MB)
    u16* A2    = tsb + 4194304;            // 2,097,152 u16 (4 MB)
    float* tkb = (float*)(A2 + 2097152);   //    32,768 f32 (128 KB)
    float* ckb = tkb + 32768;              //     2,048 f32 (8 KB)

    dim3 blk(256);
    // projections (q, kv -> bf16 ws; tk, ck -> fp32 ws)
    gemm_ff<<<dim3(16, 32), blk, 0, stream>>>(hidden, Wq,   nullptr, qb,  2048, 1024, 1024);
    gemm_ff<<<dim3(8,  32), blk, 0, stream>>>(hidden, Wkv,  nullptr, kvb, 2048, 512,  1024);
    gemm_ff<<<dim3(4,  2),  blk, 0, stream>>>(pos,    Wpos, tkb, nullptr, 128,  256,  1024);
    gemm_ff<<<dim3(4,  1),  blk, 0, stream>>>(chan,   Wchan,ckb, nullptr, 8,    256,  1024);
    // raw time_att GEMM with fused rel-shift scatter -> tsb (bf16)
    k_ta<<<dim3(16, 16, 2), blk, 0, stream>>>(qb, tkb, bias, tsb);
    // block attention -> A2 (bf16)
    k_att2<<<dim3(128, 16, 2), blk, 0, stream>>>(qb, kvb, tsb, ckb, bias, A2);
    // output projection -> fp32 d_out
    gemm_bf<<<dim3(16, 32), blk, 0, stream>>>(A2, Wproj, (float*)d_out, 2048, 1024, 1024);
}

// Round 8
// 569.782 us; speedup vs baseline: 1.9192x; 1.1880x over previous
//
#include <hip/hip_runtime.h>
#include <hip/hip_bf16.h>

#define BB 2
#define PP 128
#define CC 8
#define EE 1024
#define HH 16
#define KVHH 4
#define DD 64
#define TT 1024
#define EKVV 256

typedef unsigned short u16;
typedef unsigned int u32;
typedef __attribute__((ext_vector_type(8))) short bf16x8;
typedef __attribute__((ext_vector_type(4))) float f32x4;

__device__ __forceinline__ float b2f(u16 u) {
    u32 x = ((u32)u) << 16;
    return __uint_as_float(x);
}
__device__ __forceinline__ u16 f2b(float f) {
    u32 x = __float_as_uint(f);
    u32 r = (x + 0x7FFFu + ((x >> 16) & 1u)) >> 16;
    return (u16)r;
}

// ---------------------------------------------------------------------------
// GEMM, fp32 A and B: C[M,N] = A[M,K] @ B[K,N], fp32 accumulate.
// 64x64 tile, BK=16, 256 threads, 4x4 microtile. Cb!=null -> bf16 out.
// ---------------------------------------------------------------------------
__global__ __launch_bounds__(256) void gemm_ff(const float* __restrict__ A,
                                               const float* __restrict__ Bm,
                                               float* __restrict__ Cf,
                                               u16* __restrict__ Cb,
                                               int M, int N, int K) {
    __shared__ float As[16][68];
    __shared__ float Bs[16][68];
    int tid = threadIdx.x;
    int tx = tid & 15, ty = tid >> 4;
    int m0 = blockIdx.y * 64, n0 = blockIdx.x * 64;
    float acc[4][4];
#pragma unroll
    for (int r = 0; r < 4; r++)
#pragma unroll
        for (int c = 0; c < 4; c++) acc[r][c] = 0.f;

    int am = tid >> 2, ak = (tid & 3) << 2;
    int bk = tid >> 4, bn = (tid & 15) << 2;

    for (int k0 = 0; k0 < K; k0 += 16) {
        int row = m0 + am;
        float4 av;
        if (row < M) av = *reinterpret_cast<const float4*>(A + (size_t)row * K + k0 + ak);
        else av = make_float4(0.f, 0.f, 0.f, 0.f);
        As[ak + 0][am] = av.x;
        As[ak + 1][am] = av.y;
        As[ak + 2][am] = av.z;
        As[ak + 3][am] = av.w;
        float4 bv = *reinterpret_cast<const float4*>(Bm + (size_t)(k0 + bk) * N + n0 + bn);
        Bs[bk][bn + 0] = bv.x;
        Bs[bk][bn + 1] = bv.y;
        Bs[bk][bn + 2] = bv.z;
        Bs[bk][bn + 3] = bv.w;
        __syncthreads();
#pragma unroll
        for (int kk = 0; kk < 16; kk++) {
            float4 a4 = *reinterpret_cast<const float4*>(&As[kk][ty << 2]);
            float4 b4 = *reinterpret_cast<const float4*>(&Bs[kk][tx << 2]);
            acc[0][0] += a4.x * b4.x; acc[0][1] += a4.x * b4.y; acc[0][2] += a4.x * b4.z; acc[0][3] += a4.x * b4.w;
            acc[1][0] += a4.y * b4.x; acc[1][1] += a4.y * b4.y; acc[1][2] += a4.y * b4.z; acc[1][3] += a4.y * b4.w;
            acc[2][0] += a4.z * b4.x; acc[2][1] += a4.z * b4.y; acc[2][2] += a4.z * b4.z; acc[2][3] += a4.z * b4.w;
            acc[3][0] += a4.w * b4.x; acc[3][1] += a4.w * b4.y; acc[3][2] += a4.w * b4.z; acc[3][3] += a4.w * b4.w;
        }
        __syncthreads();
    }
#pragma unroll
    for (int r = 0; r < 4; r++) {
        int row = m0 + (ty << 2) + r;
        if (row < M) {
#pragma unroll
            for (int c = 0; c < 4; c++) {
                int col = n0 + (tx << 2) + c;
                if (Cb) Cb[(size_t)row * N + col] = f2b(acc[r][c]);
                else    Cf[(size_t)row * N + col] = acc[r][c];
            }
        }
    }
}

// ---------------------------------------------------------------------------
// GEMM, bf16 A x fp32 B -> fp32 out (final projection into fp32 d_out).
// ---------------------------------------------------------------------------
__global__ __launch_bounds__(256) void gemm_bf(const u16* __restrict__ A,
                                               const float* __restrict__ Bm,
                                               float* __restrict__ Cf,
                                               int M, int N, int K) {
    __shared__ float As[16][68];
    __shared__ float Bs[16][68];
    int tid = threadIdx.x;
    int tx = tid & 15, ty = tid >> 4;
    int m0 = blockIdx.y * 64, n0 = blockIdx.x * 64;
    float acc[4][4];
#pragma unroll
    for (int r = 0; r < 4; r++)
#pragma unroll
        for (int c = 0; c < 4; c++) acc[r][c] = 0.f;

    int am = tid >> 2, ak = (tid & 3) << 2;
    int bk = tid >> 4, bn = (tid & 15) << 2;

    for (int k0 = 0; k0 < K; k0 += 16) {
        int row = m0 + am;
        ushort4 av;
        if (row < M) av = *reinterpret_cast<const ushort4*>(A + (size_t)row * K + k0 + ak);
        else av = make_ushort4(0, 0, 0, 0);
        As[ak + 0][am] = b2f(av.x);
        As[ak + 1][am] = b2f(av.y);
        As[ak + 2][am] = b2f(av.z);
        As[ak + 3][am] = b2f(av.w);
        float4 bv = *reinterpret_cast<const float4*>(Bm + (size_t)(k0 + bk) * N + n0 + bn);
        Bs[bk][bn + 0] = bv.x;
        Bs[bk][bn + 1] = bv.y;
        Bs[bk][bn + 2] = bv.z;
        Bs[bk][bn + 3] = bv.w;
        __syncthreads();
#pragma unroll
        for (int kk = 0; kk < 16; kk++) {
            float4 a4 = *reinterpret_cast<const float4*>(&As[kk][ty << 2]);
            float4 b4 = *reinterpret_cast<const float4*>(&Bs[kk][tx << 2]);
            acc[0][0] += a4.x * b4.x; acc[0][1] += a4.x * b4.y; acc[0][2] += a4.x * b4.z; acc[0][3] += a4.x * b4.w;
            acc[1][0] += a4.y * b4.x; acc[1][1] += a4.y * b4.y; acc[1][2] += a4.y * b4.z; acc[1][3] += a4.y * b4.w;
            acc[2][0] += a4.z * b4.x; acc[2][1] += a4.z * b4.y; acc[2][2] += a4.z * b4.z; acc[2][3] += a4.z * b4.w;
            acc[3][0] += a4.w * b4.x; acc[3][1] += a4.w * b4.y; acc[3][2] += a4.w * b4.z; acc[3][3] += a4.w * b4.w;
        }
        __syncthreads();
    }
#pragma unroll
    for (int r = 0; r < 4; r++) {
        int row = m0 + (ty << 2) + r;
        if (row < M) {
#pragma unroll
            for (int c = 0; c < 4; c++) {
                int col = n0 + (tx << 2) + c;
                Cf[(size_t)row * N + col] = acc[r][c];
            }
        }
    }
}

// ---------------------------------------------------------------------------
// k_ta: raw time_att GEMM with fused rel-shift scatter (row-contiguous).
// ---------------------------------------------------------------------------
__global__ __launch_bounds__(256) void k_ta(const u16* __restrict__ qb,
                                            const float* __restrict__ tkb,
                                            const float* __restrict__ bias,
                                            u16* __restrict__ tsb) {
    __shared__ float qs[64][65];
    __shared__ float tks[128][65];
    int tid = threadIdx.x;
    int t0 = blockIdx.x * 64;
    int h = blockIdx.y, b = blockIdx.z;
    int kvh = h >> 2;

#pragma unroll
    for (int it = 0; it < 16; it++) {
        int idx = tid + it * 256;
        int row = idx >> 6, d = idx & 63;
        qs[row][d] = b2f(qb[((size_t)(b * TT + t0 + row)) * EE + h * 64 + d])
                   + bias[EKVV + kvh * 64 + d];
    }
#pragma unroll
    for (int it = 0; it < 32; it++) {
        int idx = tid + it * 256;
        int p = idx >> 6, d = idx & 63;
        tks[p][d] = tkb[p * EKVV + kvh * 64 + d];
    }
    __syncthreads();

    int tx = tid & 31, ty = tid >> 5;
    float acc[8][4];
#pragma unroll
    for (int i = 0; i < 8; i++)
#pragma unroll
        for (int j = 0; j < 4; j++) acc[i][j] = 0.f;

    for (int d = 0; d < 64; d++) {
        float tv[4];
#pragma unroll
        for (int j = 0; j < 4; j++) tv[j] = tks[tx + 32 * j][d];
#pragma unroll
        for (int i = 0; i < 8; i++) {
            float qv = qs[ty * 8 + i][d];
#pragma unroll
            for (int j = 0; j < 4; j++) acc[i][j] += qv * tv[j];
        }
    }

    size_t basebh = ((size_t)(b * HH + h)) * (TT * PP);
#pragma unroll
    for (int i = 0; i < 8; i++) {
        int tp = t0 + ty * 8 + i;
        int gbase = tp * PP + (tp >> 3) + 1 - PP;
#pragma unroll
        for (int j = 0; j < 4; j++) {
            int ppx = tx + 32 * j;
            int o = gbase + ppx;
            if (o >= 0) tsb[basebh + o] = f2b(acc[i][j]);
        }
    }
    if (tid < 64) {
        int tp = t0 + tid;
        if (tp >= 1 && tp < 128) tsb[basebh + 1025 * tp - PP] = 0;
    }
}

// ---------------------------------------------------------------------------
// k_att3: MFMA block attention. One block per (pi, h, b); 8 query rows.
// QK and PV via v_mfma_f32_16x16x32_bf16. Fragment maps (guide-verified):
//   A[m=lane&15][k=quad*8+j], B[k=quad*8+j][n=lane&15],
//   C[row=quad*4+reg][col=lane&15].
// ---------------------------------------------------------------------------
__global__ __launch_bounds__(256) void k_att3(const u16* __restrict__ qb,
                                              const u16* __restrict__ kvb,
                                              const u16* __restrict__ tsb,
                                              const float* __restrict__ ckb,
                                              const float* __restrict__ bias,
                                              u16* __restrict__ A2) {
    __shared__ __align__(16) char smem[59072];
    float* w    = (float*)(smem);            // [8][1028] fp32 scores
    u16*   Kst  = (u16*)(smem + 32896);      // [128][72] bf16 (K chunk)
    u16*   Vst  = (u16*)(smem + 32896);      // [64][136] bf16 (V chunk, transposed)
    float* wred = (float*)(smem + 32896);    // [4][8][64] cross-wave reduce
    u16*   qg   = (u16*)(smem + 51328);      // [16][72] bf16 (q+gb, rows 8-15 zero)
    float* ts8  = (float*)(smem + 53632);    // [8][128]
    float* cs8  = (float*)(smem + 57728);    // [8][8]
    float* red  = (float*)(smem + 57984);    // [256]
    float* rowm = (float*)(smem + 59008);    // [8]
    float* rowl = (float*)(smem + 59040);    // [8]

    int tid = threadIdx.x;
    int lane = tid & 63, wave = tid >> 6;
    int r16 = lane & 15, quad = lane >> 4;
    int pi = blockIdx.x, h = blockIdx.y, b = blockIdx.z;
    int kvh = h >> 2;
    int t0 = pi << 3;
    int limit = (pi + 1) << 3;
    int limitC32 = (limit + 31) & ~31;
    bool lastrow = (pi == PP - 1);
    int winLo = lastrow ? 0 : (pi - 10) << 3;
    if (winLo < 0) winLo = 0;

    // ---- stage qg (bf16, rows 8-15 zero), ts8, cs8 ----
#pragma unroll
    for (int it = 0; it < 4; it++) {
        int idx = tid + it * 256;       // 1024 = 16x64
        int r = idx >> 6, d = idx & 63;
        u16 v = 0;
        if (r < 8)
            v = f2b(b2f(qb[((size_t)(b * TT + t0 + r)) * EE + h * 64 + d]) + bias[kvh * 64 + d]);
        qg[r * 72 + d] = v;
    }
#pragma unroll
    for (int it = 0; it < 4; it++) {
        int idx = tid + it * 256;       // 1024 = 8x128
        int r = idx >> 7, ps = idx & 127;
        ts8[r * 128 + ps] = b2f(tsb[((size_t)(b * HH + h)) * (TT * PP) + (size_t)(t0 + r) * PP + ps]);
    }
    if (tid < 64) {
        int r = tid >> 3, c = tid & 7;
        int df = r - c; if (df < 0) df = -df;
        const float* ckr = ckb + (7 - df) * EKVV + kvh * 64;
        const float* cb = bias + 2 * EKVV + kvh * 64;
        const u16* q1 = qb + ((size_t)(b * TT + t0 + r)) * EE + h * 64;
        float acc = 0.f;
#pragma unroll 8
        for (int d = 0; d < 64; d++) acc += (b2f(q1[d]) + cb[d]) * ckr[d];
        cs8[r * 8 + c] = acc;
    }
    __syncthreads();

    // ---- init scores: (ts+cs)/8 for s<limit, -1e30 pad to limitC32 ----
    for (int r = 0; r < 8; r++)
        for (int s = tid; s < limitC32; s += 256)
            w[r * 1028 + s] = (s < limit)
                ? (ts8[r * 128 + (s >> 3)] + cs8[r * 8 + (s & 7)]) * 0.125f
                : -1.0e30f;

    // ---- QK via MFMA over windowed chunks ----
    bf16x8 aq0, aq1;
    {
        const u16* qp = qg + r16 * 72 + quad * 8;
        aq0 = *(const bf16x8*)(qp);
        aq1 = *(const bf16x8*)(qp + 32);
    }
    int tLo = winLo & ~15;
    for (int c0 = winLo & ~127; c0 < limit; c0 += 128) {
        __syncthreads();
        for (int idx = tid; idx < 1024; idx += 256) {
            int s = idx >> 3, part = idx & 7;
            *(uint4*)(Kst + s * 72 + part * 8) =
                *(const uint4*)(kvb + ((size_t)(b * TT + c0 + s)) * (2 * EKVV) + kvh * 64 + part * 8);
        }
        __syncthreads();
        int nBeg = tLo > c0 ? tLo : c0;
        int nEnd = min(limit, c0 + 128);
        for (int n0 = nBeg; n0 < nEnd; n0 += 16) {
            if (((n0 >> 4) & 3) != wave) continue;
            f32x4 acc = {0.f, 0.f, 0.f, 0.f};
            const u16* kp = Kst + (n0 - c0 + r16) * 72 + quad * 8;
            bf16x8 b0 = *(const bf16x8*)(kp);
            bf16x8 b1 = *(const bf16x8*)(kp + 32);
            acc = __builtin_amdgcn_mfma_f32_16x16x32_bf16(aq0, b0, acc, 0, 0, 0);
            acc = __builtin_amdgcn_mfma_f32_16x16x32_bf16(aq1, b1, acc, 0, 0, 0);
            if (quad < 2) {
                int s = n0 + r16;
                if (s >= winLo && s < limit) {
#pragma unroll
                    for (int rg = 0; rg < 4; rg++) {
                        int row = quad * 4 + rg;
                        w[row * 1028 + s] += acc[rg] * 0.125f;
                    }
                }
            }
        }
    }
    __syncthreads();

    // ---- softmax (two-pass, 32 threads per row) ----
    {
        int g = tid >> 5, l32 = tid & 31;
        float pm = -1.0e30f;
        for (int s = l32; s < limit; s += 32) pm = fmaxf(pm, w[g * 1028 + s]);
        red[tid] = pm;
        __syncthreads();
        if (tid < 8) {
            float mm = -1.0e30f;
            for (int i = 0; i < 32; i++) mm = fmaxf(mm, red[tid * 32 + i]);
            rowm[tid] = mm;
        }
        __syncthreads();
        float mr = rowm[g];
        float psum = 0.f;
        for (int s = l32; s < limitC32; s += 32) {
            float e = __expf(w[g * 1028 + s] - mr);
            w[g * 1028 + s] = e;
            psum += e;
        }
        red[tid] = psum;
        __syncthreads();
        if (tid < 8) {
            float ss = 0.f;
            for (int i = 0; i < 32; i++) ss += red[tid * 32 + i];
            rowl[tid] = ss;
        }
    }

    // ---- PV via MFMA: chunks of 128 s; wave handles k-chunk wave*32 ----
    f32x4 accv[4];
#pragma unroll
    for (int nt = 0; nt < 4; nt++) accv[nt] = (f32x4){0.f, 0.f, 0.f, 0.f};
    int s0loc = wave * 32;
    for (int c0 = 0; c0 < limit; c0 += 128) {
        __syncthreads();
        for (int idx = tid; idx < 1024; idx += 256) {
            int s = idx >> 3, part = idx & 7;
            uint4 u = *(const uint4*)(kvb + ((size_t)(b * TT + c0 + s)) * (2 * EKVV) + EKVV + kvh * 64 + part * 8);
            int d0 = part * 8;
            Vst[(d0 + 0) * 136 + s] = (u16)(u.x & 0xffff);
            Vst[(d0 + 1) * 136 + s] = (u16)(u.x >> 16);
            Vst[(d0 + 2) * 136 + s] = (u16)(u.y & 0xffff);
            Vst[(d0 + 3) * 136 + s] = (u16)(u.y >> 16);
            Vst[(d0 + 4) * 136 + s] = (u16)(u.z & 0xffff);
            Vst[(d0 + 5) * 136 + s] = (u16)(u.z >> 16);
            Vst[(d0 + 6) * 136 + s] = (u16)(u.w & 0xffff);
            Vst[(d0 + 7) * 136 + s] = (u16)(u.w >> 16);
        }
        __syncthreads();
        int s0 = c0 + s0loc;
        if (s0 < limit) {
            bf16x8 ap;
            if (r16 < 8) {
                const float* wp = w + r16 * 1028 + s0 + quad * 8;
#pragma unroll
                for (int j = 0; j < 8; j++) ap[j] = (short)f2b(wp[j]);
            } else {
#pragma unroll
                for (int j = 0; j < 8; j++) ap[j] = 0;
            }
#pragma unroll
            for (int nt = 0; nt < 4; nt++) {
                bf16x8 bv = *(const bf16x8*)(Vst + (nt * 16 + r16) * 136 + s0loc + quad * 8);
                accv[nt] = __builtin_amdgcn_mfma_f32_16x16x32_bf16(ap, bv, accv[nt], 0, 0, 0);
            }
        }
    }

    // ---- cross-wave reduce + output ----
    __syncthreads();   // all waves done with Vst
    if (quad < 2) {
#pragma unroll
        for (int nt = 0; nt < 4; nt++)
#pragma unroll
            for (int rg = 0; rg < 4; rg++) {
                int row = quad * 4 + rg;
                wred[(wave * 8 + row) * 64 + nt * 16 + r16] = accv[nt][rg];
            }
    }
    __syncthreads();
#pragma unroll
    for (int pair = 0; pair < 2; pair++) {
        int idx = tid + pair * 256;
        int r = idx >> 6, d = idx & 63;
        float sum = wred[r * 64 + d] + wred[(8 + r) * 64 + d]
                  + wred[(16 + r) * 64 + d] + wred[(24 + r) * 64 + d];
        A2[((size_t)(b * TT + t0 + r)) * EE + h * 64 + d] = f2b(sum / rowl[r]);
    }
}

extern "C" void kernel_launch(void* const* d_in, const int* in_sizes, int n_in,
                              void* d_out, int out_size, void* d_ws, size_t ws_size,
                              hipStream_t stream) {
    const float* hidden = (const float*)d_in[0];
    const float* pos    = (const float*)d_in[1];
    const float* chan   = (const float*)d_in[2];
    const float* Wq     = (const float*)d_in[3];
    const float* Wkv    = (const float*)d_in[4];
    const float* Wpos   = (const float*)d_in[5];
    const float* Wchan  = (const float*)d_in[6];
    const float* Wproj  = (const float*)d_in[7];
    const float* bias   = (const float*)d_in[8];

    // workspace carve: ~18.3 MB total
    u16* qb    = (u16*)d_ws;               // 2,097,152 u16 (4 MB)
    u16* kvb   = qb + 2097152;             // 1,048,576 u16 (2 MB)
    u16* tsb   = kvb + 1048576;            // 4,194,304 u16 (8 MB)
    u16* A2    = tsb + 4194304;            // 2,097,152 u16 (4 MB)
    float* tkb = (float*)(A2 + 2097152);   //    32,768 f32 (128 KB)
    float* ckb = tkb + 32768;              //     2,048 f32 (8 KB)

    dim3 blk(256);
    gemm_ff<<<dim3(16, 32), blk, 0, stream>>>(hidden, Wq,   nullptr, qb,  2048, 1024, 1024);
    gemm_ff<<<dim3(8,  32), blk, 0, stream>>>(hidden, Wkv,  nullptr, kvb, 2048, 512,  1024);
    gemm_ff<<<dim3(4,  2),  blk, 0, stream>>>(pos,    Wpos, tkb, nullptr, 128,  256,  1024);
    gemm_ff<<<dim3(4,  1),  blk, 0, stream>>>(chan,   Wchan,ckb, nullptr, 8,    256,  1024);
    k_ta<<<dim3(16, 16, 2), blk, 0, stream>>>(qb, tkb, bias, tsb);
    k_att3<<<dim3(128, 16, 2), blk, 0, stream>>>(qb, kvb, tsb, ckb, bias, A2);
    gemm_bf<<<dim3(16, 32), blk, 0, stream>>>(A2, Wproj, (float*)d_out, 2048, 1024, 1024);
}

// Round 9
// 498.170 us; speedup vs baseline: 2.1951x; 1.1438x over previous
//
#include <hip/hip_runtime.h>
#include <hip/hip_bf16.h>

#define BB 2
#define PP 128
#define CC 8
#define EE 1024
#define HH 16
#define KVHH 4
#define DD 64
#define TT 1024
#define EKVV 256

typedef unsigned short u16;
typedef unsigned int u32;
typedef __attribute__((ext_vector_type(8))) short bf16x8;
typedef __attribute__((ext_vector_type(4))) float f32x4;

__device__ __forceinline__ float b2f(u16 u) {
    u32 x = ((u32)u) << 16;
    return __uint_as_float(x);
}
__device__ __forceinline__ u16 f2b(float f) {
    u32 x = __float_as_uint(f);
    u32 r = (x + 0x7FFFu + ((x >> 16) & 1u)) >> 16;
    return (u16)r;
}

// ---------------------------------------------------------------------------
// GEMM, fp32 A and B (small shapes only: Wpos/Wchan projections).
// ---------------------------------------------------------------------------
__global__ __launch_bounds__(256) void gemm_ff(const float* __restrict__ A,
                                               const float* __restrict__ Bm,
                                               float* __restrict__ Cf,
                                               u16* __restrict__ Cb,
                                               int M, int N, int K) {
    __shared__ float As[16][68];
    __shared__ float Bs[16][68];
    int tid = threadIdx.x;
    int tx = tid & 15, ty = tid >> 4;
    int m0 = blockIdx.y * 64, n0 = blockIdx.x * 64;
    float acc[4][4];
#pragma unroll
    for (int r = 0; r < 4; r++)
#pragma unroll
        for (int c = 0; c < 4; c++) acc[r][c] = 0.f;

    int am = tid >> 2, ak = (tid & 3) << 2;
    int bk = tid >> 4, bn = (tid & 15) << 2;

    for (int k0 = 0; k0 < K; k0 += 16) {
        int row = m0 + am;
        float4 av;
        if (row < M) av = *reinterpret_cast<const float4*>(A + (size_t)row * K + k0 + ak);
        else av = make_float4(0.f, 0.f, 0.f, 0.f);
        As[ak + 0][am] = av.x;
        As[ak + 1][am] = av.y;
        As[ak + 2][am] = av.z;
        As[ak + 3][am] = av.w;
        float4 bv = *reinterpret_cast<const float4*>(Bm + (size_t)(k0 + bk) * N + n0 + bn);
        Bs[bk][bn + 0] = bv.x;
        Bs[bk][bn + 1] = bv.y;
        Bs[bk][bn + 2] = bv.z;
        Bs[bk][bn + 3] = bv.w;
        __syncthreads();
#pragma unroll
        for (int kk = 0; kk < 16; kk++) {
            float4 a4 = *reinterpret_cast<const float4*>(&As[kk][ty << 2]);
            float4 b4 = *reinterpret_cast<const float4*>(&Bs[kk][tx << 2]);
            acc[0][0] += a4.x * b4.x; acc[0][1] += a4.x * b4.y; acc[0][2] += a4.x * b4.z; acc[0][3] += a4.x * b4.w;
            acc[1][0] += a4.y * b4.x; acc[1][1] += a4.y * b4.y; acc[1][2] += a4.y * b4.z; acc[1][3] += a4.y * b4.w;
            acc[2][0] += a4.z * b4.x; acc[2][1] += a4.z * b4.y; acc[2][2] += a4.z * b4.z; acc[2][3] += a4.z * b4.w;
            acc[3][0] += a4.w * b4.x; acc[3][1] += a4.w * b4.y; acc[3][2] += a4.w * b4.z; acc[3][3] += a4.w * b4.w;
        }
        __syncthreads();
    }
#pragma unroll
    for (int r = 0; r < 4; r++) {
        int row = m0 + (ty << 2) + r;
        if (row < M) {
#pragma unroll
            for (int c = 0; c < 4; c++) {
                int col = n0 + (tx << 2) + c;
                if (Cb) Cb[(size_t)row * N + col] = f2b(acc[r][c]);
                else    Cf[(size_t)row * N + col] = acc[r][c];
            }
        }
    }
}

// ---------------------------------------------------------------------------
// MFMA GEMM, fused q/kv: A(2048x1024 fp32) x {Wq(1024x1024), Wkv(1024x512)}
// -> qb (bf16 2048x1024), kvb (bf16 2048x512).
// 128x128 tile, BK=32, 4 waves 2x2, 16 MFMA per wave per K-step.
// Fragment maps (validated by working k_att3):
//   A[m=lane&15][k=quad*8+j], B[k=quad*8+j][n=lane&15],
//   C[row=quad*4+reg][col=lane&15].
// ---------------------------------------------------------------------------
__global__ __launch_bounds__(256) void mgemm_qkv(const float* __restrict__ A,
                                                 const float* __restrict__ Wq,
                                                 const float* __restrict__ Wkv,
                                                 u16* __restrict__ qout,
                                                 u16* __restrict__ kvout) {
    __shared__ __align__(16) u16 As[128 * 40];
    __shared__ __align__(16) u16 Bs[128 * 40];
    int tid = threadIdx.x;
    int ntile = blockIdx.x;          // 0..11
    int m0 = blockIdx.y * 128;
    const float* B;
    u16* Cout;
    int BN, n0;
    if (ntile < 8) { B = Wq;  Cout = qout;  BN = 1024; n0 = ntile * 128; }
    else           { B = Wkv; Cout = kvout; BN = 512;  n0 = (ntile - 8) * 128; }

    int lane = tid & 63, wave = tid >> 6;
    int r16 = lane & 15, quad = lane >> 4;
    int mb = (wave >> 1) * 64, nb = (wave & 1) * 64;

    f32x4 acc[4][4];
#pragma unroll
    for (int mt = 0; mt < 4; mt++)
#pragma unroll
        for (int nt = 0; nt < 4; nt++) acc[mt][nt] = (f32x4){0.f, 0.f, 0.f, 0.f};

    for (int k0 = 0; k0 < 1024; k0 += 32) {
        __syncthreads();
        // stage A 128x32 (fp32 -> bf16)
#pragma unroll
        for (int it = 0; it < 2; it++) {
            int idx = tid + it * 256;          // 512 groups of 8
            int row = idx >> 2, kg = (idx & 3) << 3;
            const float* ap = A + (size_t)(m0 + row) * 1024 + k0 + kg;
            float4 a0 = *(const float4*)(ap);
            float4 a1 = *(const float4*)(ap + 4);
            u16 tmp[8] = {f2b(a0.x), f2b(a0.y), f2b(a0.z), f2b(a0.w),
                          f2b(a1.x), f2b(a1.y), f2b(a1.z), f2b(a1.w)};
            *(uint4*)(As + row * 40 + kg) = *(uint4*)tmp;
        }
        // stage B transposed: Bs[n][k] (fp32 -> bf16)
#pragma unroll
        for (int it = 0; it < 4; it++) {
            int idx = tid + it * 256;          // 1024 float4s
            int krow = idx >> 5, ng = (idx & 31) << 2;
            float4 bv = *(const float4*)(B + (size_t)(k0 + krow) * BN + n0 + ng);
            Bs[(ng + 0) * 40 + krow] = f2b(bv.x);
            Bs[(ng + 1) * 40 + krow] = f2b(bv.y);
            Bs[(ng + 2) * 40 + krow] = f2b(bv.z);
            Bs[(ng + 3) * 40 + krow] = f2b(bv.w);
        }
        __syncthreads();
        bf16x8 af[4], bfr[4];
#pragma unroll
        for (int mt = 0; mt < 4; mt++)
            af[mt] = *(const bf16x8*)(As + (mb + mt * 16 + r16) * 40 + quad * 8);
#pragma unroll
        for (int nt = 0; nt < 4; nt++)
            bfr[nt] = *(const bf16x8*)(Bs + (nb + nt * 16 + r16) * 40 + quad * 8);
#pragma unroll
        for (int mt = 0; mt < 4; mt++)
#pragma unroll
            for (int nt = 0; nt < 4; nt++)
                acc[mt][nt] = __builtin_amdgcn_mfma_f32_16x16x32_bf16(af[mt], bfr[nt], acc[mt][nt], 0, 0, 0);
    }
#pragma unroll
    for (int mt = 0; mt < 4; mt++)
#pragma unroll
        for (int nt = 0; nt < 4; nt++)
#pragma unroll
            for (int rg = 0; rg < 4; rg++) {
                int row = m0 + mb + mt * 16 + quad * 4 + rg;
                int col = n0 + nb + nt * 16 + r16;
                Cout[(size_t)row * BN + col] = f2b(acc[mt][nt][rg]);
            }
}

// ---------------------------------------------------------------------------
// MFMA GEMM, output projection: A2(2048x1024 bf16) x Wproj(1024x1024 fp32)
// -> fp32 d_out. Same structure as mgemm_qkv.
// ---------------------------------------------------------------------------
__global__ __launch_bounds__(256) void mgemm_proj(const u16* __restrict__ A,
                                                  const float* __restrict__ B,
                                                  float* __restrict__ Cf) {
    __shared__ __align__(16) u16 As[128 * 40];
    __shared__ __align__(16) u16 Bs[128 * 40];
    int tid = threadIdx.x;
    int n0 = blockIdx.x * 128;
    int m0 = blockIdx.y * 128;

    int lane = tid & 63, wave = tid >> 6;
    int r16 = lane & 15, quad = lane >> 4;
    int mb = (wave >> 1) * 64, nb = (wave & 1) * 64;

    f32x4 acc[4][4];
#pragma unroll
    for (int mt = 0; mt < 4; mt++)
#pragma unroll
        for (int nt = 0; nt < 4; nt++) acc[mt][nt] = (f32x4){0.f, 0.f, 0.f, 0.f};

    for (int k0 = 0; k0 < 1024; k0 += 32) {
        __syncthreads();
#pragma unroll
        for (int it = 0; it < 2; it++) {
            int idx = tid + it * 256;
            int row = idx >> 2, kg = (idx & 3) << 3;
            *(uint4*)(As + row * 40 + kg) =
                *(const uint4*)(A + (size_t)(m0 + row) * 1024 + k0 + kg);
        }
#pragma unroll
        for (int it = 0; it < 4; it++) {
            int idx = tid + it * 256;
            int krow = idx >> 5, ng = (idx & 31) << 2;
            float4 bv = *(const float4*)(B + (size_t)(k0 + krow) * 1024 + n0 + ng);
            Bs[(ng + 0) * 40 + krow] = f2b(bv.x);
            Bs[(ng + 1) * 40 + krow] = f2b(bv.y);
            Bs[(ng + 2) * 40 + krow] = f2b(bv.z);
            Bs[(ng + 3) * 40 + krow] = f2b(bv.w);
        }
        __syncthreads();
        bf16x8 af[4], bfr[4];
#pragma unroll
        for (int mt = 0; mt < 4; mt++)
            af[mt] = *(const bf16x8*)(As + (mb + mt * 16 + r16) * 40 + quad * 8);
#pragma unroll
        for (int nt = 0; nt < 4; nt++)
            bfr[nt] = *(const bf16x8*)(Bs + (nb + nt * 16 + r16) * 40 + quad * 8);
#pragma unroll
        for (int mt = 0; mt < 4; mt++)
#pragma unroll
            for (int nt = 0; nt < 4; nt++)
                acc[mt][nt] = __builtin_amdgcn_mfma_f32_16x16x32_bf16(af[mt], bfr[nt], acc[mt][nt], 0, 0, 0);
    }
#pragma unroll
    for (int mt = 0; mt < 4; mt++)
#pragma unroll
        for (int nt = 0; nt < 4; nt++)
#pragma unroll
            for (int rg = 0; rg < 4; rg++) {
                int row = m0 + mb + mt * 16 + quad * 4 + rg;
                int col = n0 + nb + nt * 16 + r16;
                Cf[(size_t)row * 1024 + col] = acc[mt][nt][rg];
            }
}

// ---------------------------------------------------------------------------
// k_ta: raw time_att GEMM with fused rel-shift scatter (row-contiguous).
// ---------------------------------------------------------------------------
__global__ __launch_bounds__(256) void k_ta(const u16* __restrict__ qb,
                                            const float* __restrict__ tkb,
                                            const float* __restrict__ bias,
                                            u16* __restrict__ tsb) {
    __shared__ float qs[64][65];
    __shared__ float tks[128][65];
    int tid = threadIdx.x;
    int t0 = blockIdx.x * 64;
    int h = blockIdx.y, b = blockIdx.z;
    int kvh = h >> 2;

#pragma unroll
    for (int it = 0; it < 16; it++) {
        int idx = tid + it * 256;
        int row = idx >> 6, d = idx & 63;
        qs[row][d] = b2f(qb[((size_t)(b * TT + t0 + row)) * EE + h * 64 + d])
                   + bias[EKVV + kvh * 64 + d];
    }
#pragma unroll
    for (int it = 0; it < 32; it++) {
        int idx = tid + it * 256;
        int p = idx >> 6, d = idx & 63;
        tks[p][d] = tkb[p * EKVV + kvh * 64 + d];
    }
    __syncthreads();

    int tx = tid & 31, ty = tid >> 5;
    float acc[8][4];
#pragma unroll
    for (int i = 0; i < 8; i++)
#pragma unroll
        for (int j = 0; j < 4; j++) acc[i][j] = 0.f;

    for (int d = 0; d < 64; d++) {
        float tv[4];
#pragma unroll
        for (int j = 0; j < 4; j++) tv[j] = tks[tx + 32 * j][d];
#pragma unroll
        for (int i = 0; i < 8; i++) {
            float qv = qs[ty * 8 + i][d];
#pragma unroll
            for (int j = 0; j < 4; j++) acc[i][j] += qv * tv[j];
        }
    }

    size_t basebh = ((size_t)(b * HH + h)) * (TT * PP);
#pragma unroll
    for (int i = 0; i < 8; i++) {
        int tp = t0 + ty * 8 + i;
        int gbase = tp * PP + (tp >> 3) + 1 - PP;
#pragma unroll
        for (int j = 0; j < 4; j++) {
            int ppx = tx + 32 * j;
            int o = gbase + ppx;
            if (o >= 0) tsb[basebh + o] = f2b(acc[i][j]);
        }
    }
    if (tid < 64) {
        int tp = t0 + tid;
        if (tp >= 1 && tp < 128) tsb[basebh + 1025 * tp - PP] = 0;
    }
}

// ---------------------------------------------------------------------------
// k_att3: MFMA block attention (unchanged from round 8).
// ---------------------------------------------------------------------------
__global__ __launch_bounds__(256) void k_att3(const u16* __restrict__ qb,
                                              const u16* __restrict__ kvb,
                                              const u16* __restrict__ tsb,
                                              const float* __restrict__ ckb,
                                              const float* __restrict__ bias,
                                              u16* __restrict__ A2) {
    __shared__ __align__(16) char smem[59072];
    float* w    = (float*)(smem);            // [8][1028] fp32 scores
    u16*   Kst  = (u16*)(smem + 32896);      // [128][72]
    u16*   Vst  = (u16*)(smem + 32896);      // [64][136]
    float* wred = (float*)(smem + 32896);    // [4][8][64]
    u16*   qg   = (u16*)(smem + 51328);      // [16][72]
    float* ts8  = (float*)(smem + 53632);    // [8][128]
    float* cs8  = (float*)(smem + 57728);    // [8][8]
    float* red  = (float*)(smem + 57984);    // [256]
    float* rowm = (float*)(smem + 59008);
    float* rowl = (float*)(smem + 59040);

    int tid = threadIdx.x;
    int lane = tid & 63, wave = tid >> 6;
    int r16 = lane & 15, quad = lane >> 4;
    int pi = blockIdx.x, h = blockIdx.y, b = blockIdx.z;
    int kvh = h >> 2;
    int t0 = pi << 3;
    int limit = (pi + 1) << 3;
    int limitC32 = (limit + 31) & ~31;
    bool lastrow = (pi == PP - 1);
    int winLo = lastrow ? 0 : (pi - 10) << 3;
    if (winLo < 0) winLo = 0;

#pragma unroll
    for (int it = 0; it < 4; it++) {
        int idx = tid + it * 256;
        int r = idx >> 6, d = idx & 63;
        u16 v = 0;
        if (r < 8)
            v = f2b(b2f(qb[((size_t)(b * TT + t0 + r)) * EE + h * 64 + d]) + bias[kvh * 64 + d]);
        qg[r * 72 + d] = v;
    }
#pragma unroll
    for (int it = 0; it < 4; it++) {
        int idx = tid + it * 256;
        int r = idx >> 7, ps = idx & 127;
        ts8[r * 128 + ps] = b2f(tsb[((size_t)(b * HH + h)) * (TT * PP) + (size_t)(t0 + r) * PP + ps]);
    }
    if (tid < 64) {
        int r = tid >> 3, c = tid & 7;
        int df = r - c; if (df < 0) df = -df;
        const float* ckr = ckb + (7 - df) * EKVV + kvh * 64;
        const float* cb = bias + 2 * EKVV + kvh * 64;
        const u16* q1 = qb + ((size_t)(b * TT + t0 + r)) * EE + h * 64;
        float acc = 0.f;
#pragma unroll 8
        for (int d = 0; d < 64; d++) acc += (b2f(q1[d]) + cb[d]) * ckr[d];
        cs8[r * 8 + c] = acc;
    }
    __syncthreads();

    for (int r = 0; r < 8; r++)
        for (int s = tid; s < limitC32; s += 256)
            w[r * 1028 + s] = (s < limit)
                ? (ts8[r * 128 + (s >> 3)] + cs8[r * 8 + (s & 7)]) * 0.125f
                : -1.0e30f;

    bf16x8 aq0, aq1;
    {
        const u16* qp = qg + r16 * 72 + quad * 8;
        aq0 = *(const bf16x8*)(qp);
        aq1 = *(const bf16x8*)(qp + 32);
    }
    int tLo = winLo & ~15;
    for (int c0 = winLo & ~127; c0 < limit; c0 += 128) {
        __syncthreads();
        for (int idx = tid; idx < 1024; idx += 256) {
            int s = idx >> 3, part = idx & 7;
            *(uint4*)(Kst + s * 72 + part * 8) =
                *(const uint4*)(kvb + ((size_t)(b * TT + c0 + s)) * (2 * EKVV) + kvh * 64 + part * 8);
        }
        __syncthreads();
        int nBeg = tLo > c0 ? tLo : c0;
        int nEnd = min(limit, c0 + 128);
        for (int n0 = nBeg; n0 < nEnd; n0 += 16) {
            if (((n0 >> 4) & 3) != wave) continue;
            f32x4 acc = {0.f, 0.f, 0.f, 0.f};
            const u16* kp = Kst + (n0 - c0 + r16) * 72 + quad * 8;
            bf16x8 b0 = *(const bf16x8*)(kp);
            bf16x8 b1 = *(const bf16x8*)(kp + 32);
            acc = __builtin_amdgcn_mfma_f32_16x16x32_bf16(aq0, b0, acc, 0, 0, 0);
            acc = __builtin_amdgcn_mfma_f32_16x16x32_bf16(aq1, b1, acc, 0, 0, 0);
            if (quad < 2) {
                int s = n0 + r16;
                if (s >= winLo && s < limit) {
#pragma unroll
                    for (int rg = 0; rg < 4; rg++) {
                        int row = quad * 4 + rg;
                        w[row * 1028 + s] += acc[rg] * 0.125f;
                    }
                }
            }
        }
    }
    __syncthreads();

    {
        int g = tid >> 5, l32 = tid & 31;
        float pm = -1.0e30f;
        for (int s = l32; s < limit; s += 32) pm = fmaxf(pm, w[g * 1028 + s]);
        red[tid] = pm;
        __syncthreads();
        if (tid < 8) {
            float mm = -1.0e30f;
            for (int i = 0; i < 32; i++) mm = fmaxf(mm, red[tid * 32 + i]);
            rowm[tid] = mm;
        }
        __syncthreads();
        float mr = rowm[g];
        float psum = 0.f;
        for (int s = l32; s < limitC32; s += 32) {
            float e = __expf(w[g * 1028 + s] - mr);
            w[g * 1028 + s] = e;
            psum += e;
        }
        red[tid] = psum;
        __syncthreads();
        if (tid < 8) {
            float ss = 0.f;
            for (int i = 0; i < 32; i++) ss += red[tid * 32 + i];
            rowl[tid] = ss;
        }
    }

    f32x4 accv[4];
#pragma unroll
    for (int nt = 0; nt < 4; nt++) accv[nt] = (f32x4){0.f, 0.f, 0.f, 0.f};
    int s0loc = wave * 32;
    for (int c0 = 0; c0 < limit; c0 += 128) {
        __syncthreads();
        for (int idx = tid; idx < 1024; idx += 256) {
            int s = idx >> 3, part = idx & 7;
            uint4 u = *(const uint4*)(kvb + ((size_t)(b * TT + c0 + s)) * (2 * EKVV) + EKVV + kvh * 64 + part * 8);
            int d0 = part * 8;
            Vst[(d0 + 0) * 136 + s] = (u16)(u.x & 0xffff);
            Vst[(d0 + 1) * 136 + s] = (u16)(u.x >> 16);
            Vst[(d0 + 2) * 136 + s] = (u16)(u.y & 0xffff);
            Vst[(d0 + 3) * 136 + s] = (u16)(u.y >> 16);
            Vst[(d0 + 4) * 136 + s] = (u16)(u.z & 0xffff);
            Vst[(d0 + 5) * 136 + s] = (u16)(u.z >> 16);
            Vst[(d0 + 6) * 136 + s] = (u16)(u.w & 0xffff);
            Vst[(d0 + 7) * 136 + s] = (u16)(u.w >> 16);
        }
        __syncthreads();
        int s0 = c0 + s0loc;
        if (s0 < limit) {
            bf16x8 ap;
            if (r16 < 8) {
                const float* wp = w + r16 * 1028 + s0 + quad * 8;
#pragma unroll
                for (int j = 0; j < 8; j++) ap[j] = (short)f2b(wp[j]);
            } else {
#pragma unroll
                for (int j = 0; j < 8; j++) ap[j] = 0;
            }
#pragma unroll
            for (int nt = 0; nt < 4; nt++) {
                bf16x8 bv = *(const bf16x8*)(Vst + (nt * 16 + r16) * 136 + s0loc + quad * 8);
                accv[nt] = __builtin_amdgcn_mfma_f32_16x16x32_bf16(ap, bv, accv[nt], 0, 0, 0);
            }
        }
    }

    __syncthreads();
    if (quad < 2) {
#pragma unroll
        for (int nt = 0; nt < 4; nt++)
#pragma unroll
            for (int rg = 0; rg < 4; rg++) {
                int row = quad * 4 + rg;
                wred[(wave * 8 + row) * 64 + nt * 16 + r16] = accv[nt][rg];
            }
    }
    __syncthreads();
#pragma unroll
    for (int pair = 0; pair < 2; pair++) {
        int idx = tid + pair * 256;
        int r = idx >> 6, d = idx & 63;
        float sum = wred[r * 64 + d] + wred[(8 + r) * 64 + d]
                  + wred[(16 + r) * 64 + d] + wred[(24 + r) * 64 + d];
        A2[((size_t)(b * TT + t0 + r)) * EE + h * 64 + d] = f2b(sum / rowl[r]);
    }
}

extern "C" void kernel_launch(void* const* d_in, const int* in_sizes, int n_in,
                              void* d_out, int out_size, void* d_ws, size_t ws_size,
                              hipStream_t stream) {
    const float* hidden = (const float*)d_in[0];
    const float* pos    = (const float*)d_in[1];
    const float* chan   = (const float*)d_in[2];
    const float* Wq     = (const float*)d_in[3];
    const float* Wkv    = (const float*)d_in[4];
    const float* Wpos   = (const float*)d_in[5];
    const float* Wchan  = (const float*)d_in[6];
    const float* Wproj  = (const float*)d_in[7];
    const float* bias   = (const float*)d_in[8];

    // workspace carve: ~18.3 MB total
    u16* qb    = (u16*)d_ws;               // 2,097,152 u16 (4 MB)
    u16* kvb   = qb + 2097152;             // 1,048,576 u16 (2 MB)
    u16* tsb   = kvb + 1048576;            // 4,194,304 u16 (8 MB)
    u16* A2    = tsb + 4194304;            // 2,097,152 u16 (4 MB)
    float* tkb = (float*)(A2 + 2097152);   //    32,768 f32 (128 KB)
    float* ckb = tkb + 32768;              //     2,048 f32 (8 KB)

    dim3 blk(256);
    // small projections (fp32 outputs, VALU)
    gemm_ff<<<dim3(4, 2), blk, 0, stream>>>(pos,  Wpos,  tkb, nullptr, 128, 256, 1024);
    gemm_ff<<<dim3(4, 1), blk, 0, stream>>>(chan, Wchan, ckb, nullptr, 8,   256, 1024);
    // fused q/kv projection via MFMA
    mgemm_qkv<<<dim3(12, 16), blk, 0, stream>>>(hidden, Wq, Wkv, qb, kvb);
    // raw time_att GEMM with fused rel-shift scatter -> tsb (bf16)
    k_ta<<<dim3(16, 16, 2), blk, 0, stream>>>(qb, tkb, bias, tsb);
    // MFMA block attention -> A2 (bf16)
    k_att3<<<dim3(128, 16, 2), blk, 0, stream>>>(qb, kvb, tsb, ckb, bias, A2);
    // output projection via MFMA -> fp32 d_out
    mgemm_proj<<<dim3(8, 16), blk, 0, stream>>>(A2, Wproj, (float*)d_out);
}

// Round 10
// 483.711 us; speedup vs baseline: 2.2607x; 1.0299x over previous
//
#include <hip/hip_runtime.h>
#include <hip/hip_bf16.h>

#define BB 2
#define PP 128
#define CC 8
#define EE 1024
#define HH 16
#define KVHH 4
#define DD 64
#define TT 1024
#define EKVV 256

typedef unsigned short u16;
typedef unsigned int u32;
typedef __attribute__((ext_vector_type(8))) short bf16x8;
typedef __attribute__((ext_vector_type(4))) float f32x4;

__device__ __forceinline__ float b2f(u16 u) {
    u32 x = ((u32)u) << 16;
    return __uint_as_float(x);
}
__device__ __forceinline__ u16 f2b(float f) {
    u32 x = __float_as_uint(f);
    u32 r = (x + 0x7FFFu + ((x >> 16) & 1u)) >> 16;
    return (u16)r;
}

// ---------------------------------------------------------------------------
// GEMM, fp32 A and B (small shapes only: Wpos/Wchan projections).
// ---------------------------------------------------------------------------
__global__ __launch_bounds__(256) void gemm_ff(const float* __restrict__ A,
                                               const float* __restrict__ Bm,
                                               float* __restrict__ Cf,
                                               u16* __restrict__ Cb,
                                               int M, int N, int K) {
    __shared__ float As[16][68];
    __shared__ float Bs[16][68];
    int tid = threadIdx.x;
    int tx = tid & 15, ty = tid >> 4;
    int m0 = blockIdx.y * 64, n0 = blockIdx.x * 64;
    float acc[4][4];
#pragma unroll
    for (int r = 0; r < 4; r++)
#pragma unroll
        for (int c = 0; c < 4; c++) acc[r][c] = 0.f;

    int am = tid >> 2, ak = (tid & 3) << 2;
    int bk = tid >> 4, bn = (tid & 15) << 2;

    for (int k0 = 0; k0 < K; k0 += 16) {
        int row = m0 + am;
        float4 av;
        if (row < M) av = *reinterpret_cast<const float4*>(A + (size_t)row * K + k0 + ak);
        else av = make_float4(0.f, 0.f, 0.f, 0.f);
        As[ak + 0][am] = av.x;
        As[ak + 1][am] = av.y;
        As[ak + 2][am] = av.z;
        As[ak + 3][am] = av.w;
        float4 bv = *reinterpret_cast<const float4*>(Bm + (size_t)(k0 + bk) * N + n0 + bn);
        Bs[bk][bn + 0] = bv.x;
        Bs[bk][bn + 1] = bv.y;
        Bs[bk][bn + 2] = bv.z;
        Bs[bk][bn + 3] = bv.w;
        __syncthreads();
#pragma unroll
        for (int kk = 0; kk < 16; kk++) {
            float4 a4 = *reinterpret_cast<const float4*>(&As[kk][ty << 2]);
            float4 b4 = *reinterpret_cast<const float4*>(&Bs[kk][tx << 2]);
            acc[0][0] += a4.x * b4.x; acc[0][1] += a4.x * b4.y; acc[0][2] += a4.x * b4.z; acc[0][3] += a4.x * b4.w;
            acc[1][0] += a4.y * b4.x; acc[1][1] += a4.y * b4.y; acc[1][2] += a4.y * b4.z; acc[1][3] += a4.y * b4.w;
            acc[2][0] += a4.z * b4.x; acc[2][1] += a4.z * b4.y; acc[2][2] += a4.z * b4.z; acc[2][3] += a4.z * b4.w;
            acc[3][0] += a4.w * b4.x; acc[3][1] += a4.w * b4.y; acc[3][2] += a4.w * b4.z; acc[3][3] += a4.w * b4.w;
        }
        __syncthreads();
    }
#pragma unroll
    for (int r = 0; r < 4; r++) {
        int row = m0 + (ty << 2) + r;
        if (row < M) {
#pragma unroll
            for (int c = 0; c < 4; c++) {
                int col = n0 + (tx << 2) + c;
                if (Cb) Cb[(size_t)row * N + col] = f2b(acc[r][c]);
                else    Cf[(size_t)row * N + col] = acc[r][c];
            }
        }
    }
}

// ---------------------------------------------------------------------------
// MFMA GEMM, fused q/kv projection (unchanged from round 9).
// ---------------------------------------------------------------------------
__global__ __launch_bounds__(256) void mgemm_qkv(const float* __restrict__ A,
                                                 const float* __restrict__ Wq,
                                                 const float* __restrict__ Wkv,
                                                 u16* __restrict__ qout,
                                                 u16* __restrict__ kvout) {
    __shared__ __align__(16) u16 As[128 * 40];
    __shared__ __align__(16) u16 Bs[128 * 40];
    int tid = threadIdx.x;
    int ntile = blockIdx.x;
    int m0 = blockIdx.y * 128;
    const float* B;
    u16* Cout;
    int BN, n0;
    if (ntile < 8) { B = Wq;  Cout = qout;  BN = 1024; n0 = ntile * 128; }
    else           { B = Wkv; Cout = kvout; BN = 512;  n0 = (ntile - 8) * 128; }

    int lane = tid & 63, wave = tid >> 6;
    int r16 = lane & 15, quad = lane >> 4;
    int mb = (wave >> 1) * 64, nb = (wave & 1) * 64;

    f32x4 acc[4][4];
#pragma unroll
    for (int mt = 0; mt < 4; mt++)
#pragma unroll
        for (int nt = 0; nt < 4; nt++) acc[mt][nt] = (f32x4){0.f, 0.f, 0.f, 0.f};

    for (int k0 = 0; k0 < 1024; k0 += 32) {
        __syncthreads();
#pragma unroll
        for (int it = 0; it < 2; it++) {
            int idx = tid + it * 256;
            int row = idx >> 2, kg = (idx & 3) << 3;
            const float* ap = A + (size_t)(m0 + row) * 1024 + k0 + kg;
            float4 a0 = *(const float4*)(ap);
            float4 a1 = *(const float4*)(ap + 4);
            u16 tmp[8] = {f2b(a0.x), f2b(a0.y), f2b(a0.z), f2b(a0.w),
                          f2b(a1.x), f2b(a1.y), f2b(a1.z), f2b(a1.w)};
            *(uint4*)(As + row * 40 + kg) = *(uint4*)tmp;
        }
#pragma unroll
        for (int it = 0; it < 4; it++) {
            int idx = tid + it * 256;
            int krow = idx >> 5, ng = (idx & 31) << 2;
            float4 bv = *(const float4*)(B + (size_t)(k0 + krow) * BN + n0 + ng);
            Bs[(ng + 0) * 40 + krow] = f2b(bv.x);
            Bs[(ng + 1) * 40 + krow] = f2b(bv.y);
            Bs[(ng + 2) * 40 + krow] = f2b(bv.z);
            Bs[(ng + 3) * 40 + krow] = f2b(bv.w);
        }
        __syncthreads();
        bf16x8 af[4], bfr[4];
#pragma unroll
        for (int mt = 0; mt < 4; mt++)
            af[mt] = *(const bf16x8*)(As + (mb + mt * 16 + r16) * 40 + quad * 8);
#pragma unroll
        for (int nt = 0; nt < 4; nt++)
            bfr[nt] = *(const bf16x8*)(Bs + (nb + nt * 16 + r16) * 40 + quad * 8);
#pragma unroll
        for (int mt = 0; mt < 4; mt++)
#pragma unroll
            for (int nt = 0; nt < 4; nt++)
                acc[mt][nt] = __builtin_amdgcn_mfma_f32_16x16x32_bf16(af[mt], bfr[nt], acc[mt][nt], 0, 0, 0);
    }
#pragma unroll
    for (int mt = 0; mt < 4; mt++)
#pragma unroll
        for (int nt = 0; nt < 4; nt++)
#pragma unroll
            for (int rg = 0; rg < 4; rg++) {
                int row = m0 + mb + mt * 16 + quad * 4 + rg;
                int col = n0 + nb + nt * 16 + r16;
                Cout[(size_t)row * BN + col] = f2b(acc[mt][nt][rg]);
            }
}

// ---------------------------------------------------------------------------
// MFMA GEMM, output projection (unchanged from round 9).
// ---------------------------------------------------------------------------
__global__ __launch_bounds__(256) void mgemm_proj(const u16* __restrict__ A,
                                                  const float* __restrict__ B,
                                                  float* __restrict__ Cf) {
    __shared__ __align__(16) u16 As[128 * 40];
    __shared__ __align__(16) u16 Bs[128 * 40];
    int tid = threadIdx.x;
    int n0 = blockIdx.x * 128;
    int m0 = blockIdx.y * 128;

    int lane = tid & 63, wave = tid >> 6;
    int r16 = lane & 15, quad = lane >> 4;
    int mb = (wave >> 1) * 64, nb = (wave & 1) * 64;

    f32x4 acc[4][4];
#pragma unroll
    for (int mt = 0; mt < 4; mt++)
#pragma unroll
        for (int nt = 0; nt < 4; nt++) acc[mt][nt] = (f32x4){0.f, 0.f, 0.f, 0.f};

    for (int k0 = 0; k0 < 1024; k0 += 32) {
        __syncthreads();
#pragma unroll
        for (int it = 0; it < 2; it++) {
            int idx = tid + it * 256;
            int row = idx >> 2, kg = (idx & 3) << 3;
            *(uint4*)(As + row * 40 + kg) =
                *(const uint4*)(A + (size_t)(m0 + row) * 1024 + k0 + kg);
        }
#pragma unroll
        for (int it = 0; it < 4; it++) {
            int idx = tid + it * 256;
            int krow = idx >> 5, ng = (idx & 31) << 2;
            float4 bv = *(const float4*)(B + (size_t)(k0 + krow) * 1024 + n0 + ng);
            Bs[(ng + 0) * 40 + krow] = f2b(bv.x);
            Bs[(ng + 1) * 40 + krow] = f2b(bv.y);
            Bs[(ng + 2) * 40 + krow] = f2b(bv.z);
            Bs[(ng + 3) * 40 + krow] = f2b(bv.w);
        }
        __syncthreads();
        bf16x8 af[4], bfr[4];
#pragma unroll
        for (int mt = 0; mt < 4; mt++)
            af[mt] = *(const bf16x8*)(As + (mb + mt * 16 + r16) * 40 + quad * 8);
#pragma unroll
        for (int nt = 0; nt < 4; nt++)
            bfr[nt] = *(const bf16x8*)(Bs + (nb + nt * 16 + r16) * 40 + quad * 8);
#pragma unroll
        for (int mt = 0; mt < 4; mt++)
#pragma unroll
            for (int nt = 0; nt < 4; nt++)
                acc[mt][nt] = __builtin_amdgcn_mfma_f32_16x16x32_bf16(af[mt], bfr[nt], acc[mt][nt], 0, 0, 0);
    }
#pragma unroll
    for (int mt = 0; mt < 4; mt++)
#pragma unroll
        for (int nt = 0; nt < 4; nt++)
#pragma unroll
            for (int rg = 0; rg < 4; rg++) {
                int row = m0 + mb + mt * 16 + quad * 4 + rg;
                int col = n0 + nb + nt * 16 + r16;
                Cf[(size_t)row * 1024 + col] = acc[mt][nt][rg];
            }
}

// ---------------------------------------------------------------------------
// mk_ta: MFMA time_att with fused rel-shift scatter.
// Per (b,h): C[t][p] = (q[t]+tb) . tk[p], K=64. Block = 128x128 tile,
// grid (8, 16, 2). Shifted flat index = t*128 + t/8 + 1 - 128 + p (skip <0);
// zero slots 1025*t-128 (t in 1..127) written by block x==0.
// ---------------------------------------------------------------------------
__global__ __launch_bounds__(256) void mk_ta(const u16* __restrict__ qb,
                                             const float* __restrict__ tkb,
                                             const float* __restrict__ bias,
                                             u16* __restrict__ tsb) {
    __shared__ __align__(16) u16 qs[128 * 72];
    __shared__ __align__(16) u16 tks[128 * 72];
    int tid = threadIdx.x;
    int t0 = blockIdx.x * 128;
    int h = blockIdx.y, b = blockIdx.z;
    int kvh = h >> 2;

    // stage qg = bf16(q + tb): 128 rows x 64 d
#pragma unroll
    for (int it = 0; it < 4; it++) {
        int idx = tid + it * 256;        // 1024 groups of 8
        int r = idx >> 3, dg = (idx & 7) << 3;
        uint4 u = *(const uint4*)(qb + ((size_t)(b * TT + t0 + r)) * EE + h * 64 + dg);
        u16 tmp[8]; *(uint4*)tmp = u;
        u16 outv[8];
#pragma unroll
        for (int j = 0; j < 8; j++) outv[j] = f2b(b2f(tmp[j]) + bias[EKVV + kvh * 64 + dg + j]);
        *(uint4*)(qs + r * 72 + dg) = *(uint4*)outv;
    }
    // stage tk (fp32 -> bf16): 128 p-rows x 64 d
#pragma unroll
    for (int it = 0; it < 4; it++) {
        int idx = tid + it * 256;
        int p = idx >> 3, dg = (idx & 7) << 3;
        const float* tp = tkb + p * EKVV + kvh * 64 + dg;
        float4 a0 = *(const float4*)(tp);
        float4 a1 = *(const float4*)(tp + 4);
        u16 outv[8] = {f2b(a0.x), f2b(a0.y), f2b(a0.z), f2b(a0.w),
                       f2b(a1.x), f2b(a1.y), f2b(a1.z), f2b(a1.w)};
        *(uint4*)(tks + p * 72 + dg) = *(uint4*)outv;
    }
    __syncthreads();

    int lane = tid & 63, wave = tid >> 6;
    int r16 = lane & 15, quad = lane >> 4;
    int mb = (wave >> 1) * 64, nb = (wave & 1) * 64;

    f32x4 acc[4][4];
#pragma unroll
    for (int mt = 0; mt < 4; mt++)
#pragma unroll
        for (int nt = 0; nt < 4; nt++) acc[mt][nt] = (f32x4){0.f, 0.f, 0.f, 0.f};

#pragma unroll
    for (int k0 = 0; k0 < 64; k0 += 32) {
        bf16x8 af[4], bfr[4];
#pragma unroll
        for (int mt = 0; mt < 4; mt++)
            af[mt] = *(const bf16x8*)(qs + (mb + mt * 16 + r16) * 72 + k0 + quad * 8);
#pragma unroll
        for (int nt = 0; nt < 4; nt++)
            bfr[nt] = *(const bf16x8*)(tks + (nb + nt * 16 + r16) * 72 + k0 + quad * 8);
#pragma unroll
        for (int mt = 0; mt < 4; mt++)
#pragma unroll
            for (int nt = 0; nt < 4; nt++)
                acc[mt][nt] = __builtin_amdgcn_mfma_f32_16x16x32_bf16(af[mt], bfr[nt], acc[mt][nt], 0, 0, 0);
    }

    size_t basebh = ((size_t)(b * HH + h)) * (TT * PP);
#pragma unroll
    for (int mt = 0; mt < 4; mt++)
#pragma unroll
        for (int nt = 0; nt < 4; nt++)
#pragma unroll
            for (int rg = 0; rg < 4; rg++) {
                int tp = t0 + mb + mt * 16 + quad * 4 + rg;
                int ppx = nb + nt * 16 + r16;
                int o = tp * PP + (tp >> 3) + 1 - PP + ppx;
                if (o >= 0) tsb[basebh + o] = f2b(acc[mt][nt][rg]);
            }
    if (blockIdx.x == 0 && tid < 127) {
        int tp = tid + 1;
        tsb[basebh + 1025 * tp - PP] = 0;
    }
}

// ---------------------------------------------------------------------------
// k_att3: MFMA block attention. Vst stride 136 -> 138 (bank-conflict fix:
// d-group stride 8*69=552 = 8 mod 32 words -> 2-way instead of 8-way).
// ---------------------------------------------------------------------------
__global__ __launch_bounds__(256) void k_att3(const u16* __restrict__ qb,
                                              const u16* __restrict__ kvb,
                                              const u16* __restrict__ tsb,
                                              const float* __restrict__ ckb,
                                              const float* __restrict__ bias,
                                              u16* __restrict__ A2) {
    __shared__ __align__(16) char smem[59072];
    float* w    = (float*)(smem);            // [8][1028] fp32 scores
    u16*   Kst  = (u16*)(smem + 32896);      // [128][72]
    u16*   Vst  = (u16*)(smem + 32896);      // [64][138]  (aliased)
    float* wred = (float*)(smem + 32896);    // [4][8][64] (aliased)
    u16*   qg   = (u16*)(smem + 51328);      // [16][72]
    float* ts8  = (float*)(smem + 53632);    // [8][128]
    float* cs8  = (float*)(smem + 57728);    // [8][8]
    float* red  = (float*)(smem + 57984);    // [256]
    float* rowm = (float*)(smem + 59008);
    float* rowl = (float*)(smem + 59040);

    int tid = threadIdx.x;
    int lane = tid & 63, wave = tid >> 6;
    int r16 = lane & 15, quad = lane >> 4;
    int pi = blockIdx.x, h = blockIdx.y, b = blockIdx.z;
    int kvh = h >> 2;
    int t0 = pi << 3;
    int limit = (pi + 1) << 3;
    int limitC32 = (limit + 31) & ~31;
    bool lastrow = (pi == PP - 1);
    int winLo = lastrow ? 0 : (pi - 10) << 3;
    if (winLo < 0) winLo = 0;

#pragma unroll
    for (int it = 0; it < 4; it++) {
        int idx = tid + it * 256;
        int r = idx >> 6, d = idx & 63;
        u16 v = 0;
        if (r < 8)
            v = f2b(b2f(qb[((size_t)(b * TT + t0 + r)) * EE + h * 64 + d]) + bias[kvh * 64 + d]);
        qg[r * 72 + d] = v;
    }
#pragma unroll
    for (int it = 0; it < 4; it++) {
        int idx = tid + it * 256;
        int r = idx >> 7, ps = idx & 127;
        ts8[r * 128 + ps] = b2f(tsb[((size_t)(b * HH + h)) * (TT * PP) + (size_t)(t0 + r) * PP + ps]);
    }
    if (tid < 64) {
        int r = tid >> 3, c = tid & 7;
        int df = r - c; if (df < 0) df = -df;
        const float* ckr = ckb + (7 - df) * EKVV + kvh * 64;
        const float* cb = bias + 2 * EKVV + kvh * 64;
        const u16* q1 = qb + ((size_t)(b * TT + t0 + r)) * EE + h * 64;
        float acc = 0.f;
#pragma unroll 8
        for (int d = 0; d < 64; d++) acc += (b2f(q1[d]) + cb[d]) * ckr[d];
        cs8[r * 8 + c] = acc;
    }
    __syncthreads();

    for (int r = 0; r < 8; r++)
        for (int s = tid; s < limitC32; s += 256)
            w[r * 1028 + s] = (s < limit)
                ? (ts8[r * 128 + (s >> 3)] + cs8[r * 8 + (s & 7)]) * 0.125f
                : -1.0e30f;

    bf16x8 aq0, aq1;
    {
        const u16* qp = qg + r16 * 72 + quad * 8;
        aq0 = *(const bf16x8*)(qp);
        aq1 = *(const bf16x8*)(qp + 32);
    }
    int tLo = winLo & ~15;
    for (int c0 = winLo & ~127; c0 < limit; c0 += 128) {
        __syncthreads();
        for (int idx = tid; idx < 1024; idx += 256) {
            int s = idx >> 3, part = idx & 7;
            *(uint4*)(Kst + s * 72 + part * 8) =
                *(const uint4*)(kvb + ((size_t)(b * TT + c0 + s)) * (2 * EKVV) + kvh * 64 + part * 8);
        }
        __syncthreads();
        int nBeg = tLo > c0 ? tLo : c0;
        int nEnd = min(limit, c0 + 128);
        for (int n0 = nBeg; n0 < nEnd; n0 += 16) {
            if (((n0 >> 4) & 3) != wave) continue;
            f32x4 acc = {0.f, 0.f, 0.f, 0.f};
            const u16* kp = Kst + (n0 - c0 + r16) * 72 + quad * 8;
            bf16x8 b0 = *(const bf16x8*)(kp);
            bf16x8 b1 = *(const bf16x8*)(kp + 32);
            acc = __builtin_amdgcn_mfma_f32_16x16x32_bf16(aq0, b0, acc, 0, 0, 0);
            acc = __builtin_amdgcn_mfma_f32_16x16x32_bf16(aq1, b1, acc, 0, 0, 0);
            if (quad < 2) {
                int s = n0 + r16;
                if (s >= winLo && s < limit) {
#pragma unroll
                    for (int rg = 0; rg < 4; rg++) {
                        int row = quad * 4 + rg;
                        w[row * 1028 + s] += acc[rg] * 0.125f;
                    }
                }
            }
        }
    }
    __syncthreads();

    {
        int g = tid >> 5, l32 = tid & 31;
        float pm = -1.0e30f;
        for (int s = l32; s < limit; s += 32) pm = fmaxf(pm, w[g * 1028 + s]);
        red[tid] = pm;
        __syncthreads();
        if (tid < 8) {
            float mm = -1.0e30f;
            for (int i = 0; i < 32; i++) mm = fmaxf(mm, red[tid * 32 + i]);
            rowm[tid] = mm;
        }
        __syncthreads();
        float mr = rowm[g];
        float psum = 0.f;
        for (int s = l32; s < limitC32; s += 32) {
            float e = __expf(w[g * 1028 + s] - mr);
            w[g * 1028 + s] = e;
            psum += e;
        }
        red[tid] = psum;
        __syncthreads();
        if (tid < 8) {
            float ss = 0.f;
            for (int i = 0; i < 32; i++) ss += red[tid * 32 + i];
            rowl[tid] = ss;
        }
    }

    f32x4 accv[4];
#pragma unroll
    for (int nt = 0; nt < 4; nt++) accv[nt] = (f32x4){0.f, 0.f, 0.f, 0.f};
    int s0loc = wave * 32;
    for (int c0 = 0; c0 < limit; c0 += 128) {
        __syncthreads();
        for (int idx = tid; idx < 1024; idx += 256) {
            int s = idx >> 3, part = idx & 7;
            uint4 u = *(const uint4*)(kvb + ((size_t)(b * TT + c0 + s)) * (2 * EKVV) + EKVV + kvh * 64 + part * 8);
            int d0 = part * 8;
            Vst[(d0 + 0) * 138 + s] = (u16)(u.x & 0xffff);
            Vst[(d0 + 1) * 138 + s] = (u16)(u.x >> 16);
            Vst[(d0 + 2) * 138 + s] = (u16)(u.y & 0xffff);
            Vst[(d0 + 3) * 138 + s] = (u16)(u.y >> 16);
            Vst[(d0 + 4) * 138 + s] = (u16)(u.z & 0xffff);
            Vst[(d0 + 5) * 138 + s] = (u16)(u.z >> 16);
            Vst[(d0 + 6) * 138 + s] = (u16)(u.w & 0xffff);
            Vst[(d0 + 7) * 138 + s] = (u16)(u.w >> 16);
        }
        __syncthreads();
        int s0 = c0 + s0loc;
        if (s0 < limit) {
            bf16x8 ap;
            if (r16 < 8) {
                const float* wp = w + r16 * 1028 + s0 + quad * 8;
#pragma unroll
                for (int j = 0; j < 8; j++) ap[j] = (short)f2b(wp[j]);
            } else {
#pragma unroll
                for (int j = 0; j < 8; j++) ap[j] = 0;
            }
#pragma unroll
            for (int nt = 0; nt < 4; nt++) {
                bf16x8 bv = *(const bf16x8*)(Vst + (nt * 16 + r16) * 138 + s0loc + quad * 8);
                accv[nt] = __builtin_amdgcn_mfma_f32_16x16x32_bf16(ap, bv, accv[nt], 0, 0, 0);
            }
        }
    }

    __syncthreads();
    if (quad < 2) {
#pragma unroll
        for (int nt = 0; nt < 4; nt++)
#pragma unroll
            for (int rg = 0; rg < 4; rg++) {
                int row = quad * 4 + rg;
                wred[(wave * 8 + row) * 64 + nt * 16 + r16] = accv[nt][rg];
            }
    }
    __syncthreads();
#pragma unroll
    for (int pair = 0; pair < 2; pair++) {
        int idx = tid + pair * 256;
        int r = idx >> 6, d = idx & 63;
        float sum = wred[r * 64 + d] + wred[(8 + r) * 64 + d]
                  + wred[(16 + r) * 64 + d] + wred[(24 + r) * 64 + d];
        A2[((size_t)(b * TT + t0 + r)) * EE + h * 64 + d] = f2b(sum / rowl[r]);
    }
}

extern "C" void kernel_launch(void* const* d_in, const int* in_sizes, int n_in,
                              void* d_out, int out_size, void* d_ws, size_t ws_size,
                              hipStream_t stream) {
    const float* hidden = (const float*)d_in[0];
    const float* pos    = (const float*)d_in[1];
    const float* chan   = (const float*)d_in[2];
    const float* Wq     = (const float*)d_in[3];
    const float* Wkv    = (const float*)d_in[4];
    const float* Wpos   = (const float*)d_in[5];
    const float* Wchan  = (const float*)d_in[6];
    const float* Wproj  = (const float*)d_in[7];
    const float* bias   = (const float*)d_in[8];

    // workspace carve: ~18.3 MB total
    u16* qb    = (u16*)d_ws;               // 2,097,152 u16 (4 MB)
    u16* kvb   = qb + 2097152;             // 1,048,576 u16 (2 MB)
    u16* tsb   = kvb + 1048576;            // 4,194,304 u16 (8 MB)
    u16* A2    = tsb + 4194304;            // 2,097,152 u16 (4 MB)
    float* tkb = (float*)(A2 + 2097152);   //    32,768 f32 (128 KB)
    float* ckb = tkb + 32768;              //     2,048 f32 (8 KB)

    dim3 blk(256);
    // small projections (fp32 outputs, VALU)
    gemm_ff<<<dim3(4, 2), blk, 0, stream>>>(pos,  Wpos,  tkb, nullptr, 128, 256, 1024);
    gemm_ff<<<dim3(4, 1), blk, 0, stream>>>(chan, Wchan, ckb, nullptr, 8,   256, 1024);
    // fused q/kv projection via MFMA
    mgemm_qkv<<<dim3(12, 16), blk, 0, stream>>>(hidden, Wq, Wkv, qb, kvb);
    // MFMA time_att with fused rel-shift scatter -> tsb (bf16)
    mk_ta<<<dim3(8, 16, 2), blk, 0, stream>>>(qb, tkb, bias, tsb);
    // MFMA block attention -> A2 (bf16)
    k_att3<<<dim3(128, 16, 2), blk, 0, stream>>>(qb, kvb, tsb, ckb, bias, A2);
    // output projection via MFMA -> fp32 d_out
    mgemm_proj<<<dim3(8, 16), blk, 0, stream>>>(A2, Wproj, (float*)d_out);
}

// Round 11
// 383.954 us; speedup vs baseline: 2.8481x; 1.2598x over previous
//
#include <hip/hip_runtime.h>
#include <hip/hip_bf16.h>

#define BB 2
#define PP 128
#define CC 8
#define EE 1024
#define HH 16
#define KVHH 4
#define DD 64
#define TT 1024
#define EKVV 256

typedef unsigned short u16;
typedef unsigned int u32;
typedef __attribute__((ext_vector_type(8))) short bf16x8;
typedef __attribute__((ext_vector_type(4))) float f32x4;

__device__ __forceinline__ float b2f(u16 u) {
    u32 x = ((u32)u) << 16;
    return __uint_as_float(x);
}
__device__ __forceinline__ u16 f2b(float f) {
    u32 x = __float_as_uint(f);
    u32 r = (x + 0x7FFFu + ((x >> 16) & 1u)) >> 16;
    return (u16)r;
}

// ---------------------------------------------------------------------------
// GEMM, fp32 A and B (small shapes only: Wpos/Wchan projections).
// ---------------------------------------------------------------------------
__global__ __launch_bounds__(256) void gemm_ff(const float* __restrict__ A,
                                               const float* __restrict__ Bm,
                                               float* __restrict__ Cf,
                                               u16* __restrict__ Cb,
                                               int M, int N, int K) {
    __shared__ float As[16][68];
    __shared__ float Bs[16][68];
    int tid = threadIdx.x;
    int tx = tid & 15, ty = tid >> 4;
    int m0 = blockIdx.y * 64, n0 = blockIdx.x * 64;
    float acc[4][4];
#pragma unroll
    for (int r = 0; r < 4; r++)
#pragma unroll
        for (int c = 0; c < 4; c++) acc[r][c] = 0.f;

    int am = tid >> 2, ak = (tid & 3) << 2;
    int bk = tid >> 4, bn = (tid & 15) << 2;

    for (int k0 = 0; k0 < K; k0 += 16) {
        int row = m0 + am;
        float4 av;
        if (row < M) av = *reinterpret_cast<const float4*>(A + (size_t)row * K + k0 + ak);
        else av = make_float4(0.f, 0.f, 0.f, 0.f);
        As[ak + 0][am] = av.x;
        As[ak + 1][am] = av.y;
        As[ak + 2][am] = av.z;
        As[ak + 3][am] = av.w;
        float4 bv = *reinterpret_cast<const float4*>(Bm + (size_t)(k0 + bk) * N + n0 + bn);
        Bs[bk][bn + 0] = bv.x;
        Bs[bk][bn + 1] = bv.y;
        Bs[bk][bn + 2] = bv.z;
        Bs[bk][bn + 3] = bv.w;
        __syncthreads();
#pragma unroll
        for (int kk = 0; kk < 16; kk++) {
            float4 a4 = *reinterpret_cast<const float4*>(&As[kk][ty << 2]);
            float4 b4 = *reinterpret_cast<const float4*>(&Bs[kk][tx << 2]);
            acc[0][0] += a4.x * b4.x; acc[0][1] += a4.x * b4.y; acc[0][2] += a4.x * b4.z; acc[0][3] += a4.x * b4.w;
            acc[1][0] += a4.y * b4.x; acc[1][1] += a4.y * b4.y; acc[1][2] += a4.y * b4.z; acc[1][3] += a4.y * b4.w;
            acc[2][0] += a4.z * b4.x; acc[2][1] += a4.z * b4.y; acc[2][2] += a4.z * b4.z; acc[2][3] += a4.z * b4.w;
            acc[3][0] += a4.w * b4.x; acc[3][1] += a4.w * b4.y; acc[3][2] += a4.w * b4.z; acc[3][3] += a4.w * b4.w;
        }
        __syncthreads();
    }
#pragma unroll
    for (int r = 0; r < 4; r++) {
        int row = m0 + (ty << 2) + r;
        if (row < M) {
#pragma unroll
            for (int c = 0; c < 4; c++) {
                int col = n0 + (tx << 2) + c;
                if (Cb) Cb[(size_t)row * N + col] = f2b(acc[r][c]);
                else    Cf[(size_t)row * N + col] = acc[r][c];
            }
        }
    }
}

// ---------------------------------------------------------------------------
// MFMA GEMM, fused q/kv projection (unchanged).
// ---------------------------------------------------------------------------
__global__ __launch_bounds__(256) void mgemm_qkv(const float* __restrict__ A,
                                                 const float* __restrict__ Wq,
                                                 const float* __restrict__ Wkv,
                                                 u16* __restrict__ qout,
                                                 u16* __restrict__ kvout) {
    __shared__ __align__(16) u16 As[128 * 40];
    __shared__ __align__(16) u16 Bs[128 * 40];
    int tid = threadIdx.x;
    int ntile = blockIdx.x;
    int m0 = blockIdx.y * 128;
    const float* B;
    u16* Cout;
    int BN, n0;
    if (ntile < 8) { B = Wq;  Cout = qout;  BN = 1024; n0 = ntile * 128; }
    else           { B = Wkv; Cout = kvout; BN = 512;  n0 = (ntile - 8) * 128; }

    int lane = tid & 63, wave = tid >> 6;
    int r16 = lane & 15, quad = lane >> 4;
    int mb = (wave >> 1) * 64, nb = (wave & 1) * 64;

    f32x4 acc[4][4];
#pragma unroll
    for (int mt = 0; mt < 4; mt++)
#pragma unroll
        for (int nt = 0; nt < 4; nt++) acc[mt][nt] = (f32x4){0.f, 0.f, 0.f, 0.f};

    for (int k0 = 0; k0 < 1024; k0 += 32) {
        __syncthreads();
#pragma unroll
        for (int it = 0; it < 2; it++) {
            int idx = tid + it * 256;
            int row = idx >> 2, kg = (idx & 3) << 3;
            const float* ap = A + (size_t)(m0 + row) * 1024 + k0 + kg;
            float4 a0 = *(const float4*)(ap);
            float4 a1 = *(const float4*)(ap + 4);
            u16 tmp[8] = {f2b(a0.x), f2b(a0.y), f2b(a0.z), f2b(a0.w),
                          f2b(a1.x), f2b(a1.y), f2b(a1.z), f2b(a1.w)};
            *(uint4*)(As + row * 40 + kg) = *(uint4*)tmp;
        }
#pragma unroll
        for (int it = 0; it < 4; it++) {
            int idx = tid + it * 256;
            int krow = idx >> 5, ng = (idx & 31) << 2;
            float4 bv = *(const float4*)(B + (size_t)(k0 + krow) * BN + n0 + ng);
            Bs[(ng + 0) * 40 + krow] = f2b(bv.x);
            Bs[(ng + 1) * 40 + krow] = f2b(bv.y);
            Bs[(ng + 2) * 40 + krow] = f2b(bv.z);
            Bs[(ng + 3) * 40 + krow] = f2b(bv.w);
        }
        __syncthreads();
        bf16x8 af[4], bfr[4];
#pragma unroll
        for (int mt = 0; mt < 4; mt++)
            af[mt] = *(const bf16x8*)(As + (mb + mt * 16 + r16) * 40 + quad * 8);
#pragma unroll
        for (int nt = 0; nt < 4; nt++)
            bfr[nt] = *(const bf16x8*)(Bs + (nb + nt * 16 + r16) * 40 + quad * 8);
#pragma unroll
        for (int mt = 0; mt < 4; mt++)
#pragma unroll
            for (int nt = 0; nt < 4; nt++)
                acc[mt][nt] = __builtin_amdgcn_mfma_f32_16x16x32_bf16(af[mt], bfr[nt], acc[mt][nt], 0, 0, 0);
    }
#pragma unroll
    for (int mt = 0; mt < 4; mt++)
#pragma unroll
        for (int nt = 0; nt < 4; nt++)
#pragma unroll
            for (int rg = 0; rg < 4; rg++) {
                int row = m0 + mb + mt * 16 + quad * 4 + rg;
                int col = n0 + nb + nt * 16 + r16;
                Cout[(size_t)row * BN + col] = f2b(acc[mt][nt][rg]);
            }
}

// ---------------------------------------------------------------------------
// MFMA GEMM, output projection (unchanged).
// ---------------------------------------------------------------------------
__global__ __launch_bounds__(256) void mgemm_proj(const u16* __restrict__ A,
                                                  const float* __restrict__ B,
                                                  float* __restrict__ Cf) {
    __shared__ __align__(16) u16 As[128 * 40];
    __shared__ __align__(16) u16 Bs[128 * 40];
    int tid = threadIdx.x;
    int n0 = blockIdx.x * 128;
    int m0 = blockIdx.y * 128;

    int lane = tid & 63, wave = tid >> 6;
    int r16 = lane & 15, quad = lane >> 4;
    int mb = (wave >> 1) * 64, nb = (wave & 1) * 64;

    f32x4 acc[4][4];
#pragma unroll
    for (int mt = 0; mt < 4; mt++)
#pragma unroll
        for (int nt = 0; nt < 4; nt++) acc[mt][nt] = (f32x4){0.f, 0.f, 0.f, 0.f};

    for (int k0 = 0; k0 < 1024; k0 += 32) {
        __syncthreads();
#pragma unroll
        for (int it = 0; it < 2; it++) {
            int idx = tid + it * 256;
            int row = idx >> 2, kg = (idx & 3) << 3;
            *(uint4*)(As + row * 40 + kg) =
                *(const uint4*)(A + (size_t)(m0 + row) * 1024 + k0 + kg);
        }
#pragma unroll
        for (int it = 0; it < 4; it++) {
            int idx = tid + it * 256;
            int krow = idx >> 5, ng = (idx & 31) << 2;
            float4 bv = *(const float4*)(B + (size_t)(k0 + krow) * 1024 + n0 + ng);
            Bs[(ng + 0) * 40 + krow] = f2b(bv.x);
            Bs[(ng + 1) * 40 + krow] = f2b(bv.y);
            Bs[(ng + 2) * 40 + krow] = f2b(bv.z);
            Bs[(ng + 3) * 40 + krow] = f2b(bv.w);
        }
        __syncthreads();
        bf16x8 af[4], bfr[4];
#pragma unroll
        for (int mt = 0; mt < 4; mt++)
            af[mt] = *(const bf16x8*)(As + (mb + mt * 16 + r16) * 40 + quad * 8);
#pragma unroll
        for (int nt = 0; nt < 4; nt++)
            bfr[nt] = *(const bf16x8*)(Bs + (nb + nt * 16 + r16) * 40 + quad * 8);
#pragma unroll
        for (int mt = 0; mt < 4; mt++)
#pragma unroll
            for (int nt = 0; nt < 4; nt++)
                acc[mt][nt] = __builtin_amdgcn_mfma_f32_16x16x32_bf16(af[mt], bfr[nt], acc[mt][nt], 0, 0, 0);
    }
#pragma unroll
    for (int mt = 0; mt < 4; mt++)
#pragma unroll
        for (int nt = 0; nt < 4; nt++)
#pragma unroll
            for (int rg = 0; rg < 4; rg++) {
                int row = m0 + mb + mt * 16 + quad * 4 + rg;
                int col = n0 + nb + nt * 16 + r16;
                Cf[(size_t)row * 1024 + col] = acc[mt][nt][rg];
            }
}

// ---------------------------------------------------------------------------
// mk_ta: MFMA time_att with fused rel-shift scatter (unchanged).
// ---------------------------------------------------------------------------
__global__ __launch_bounds__(256) void mk_ta(const u16* __restrict__ qb,
                                             const float* __restrict__ tkb,
                                             const float* __restrict__ bias,
                                             u16* __restrict__ tsb) {
    __shared__ __align__(16) u16 qs[128 * 72];
    __shared__ __align__(16) u16 tks[128 * 72];
    int tid = threadIdx.x;
    int t0 = blockIdx.x * 128;
    int h = blockIdx.y, b = blockIdx.z;
    int kvh = h >> 2;

#pragma unroll
    for (int it = 0; it < 4; it++) {
        int idx = tid + it * 256;
        int r = idx >> 3, dg = (idx & 7) << 3;
        uint4 u = *(const uint4*)(qb + ((size_t)(b * TT + t0 + r)) * EE + h * 64 + dg);
        u16 tmp[8]; *(uint4*)tmp = u;
        u16 outv[8];
#pragma unroll
        for (int j = 0; j < 8; j++) outv[j] = f2b(b2f(tmp[j]) + bias[EKVV + kvh * 64 + dg + j]);
        *(uint4*)(qs + r * 72 + dg) = *(uint4*)outv;
    }
#pragma unroll
    for (int it = 0; it < 4; it++) {
        int idx = tid + it * 256;
        int p = idx >> 3, dg = (idx & 7) << 3;
        const float* tp = tkb + p * EKVV + kvh * 64 + dg;
        float4 a0 = *(const float4*)(tp);
        float4 a1 = *(const float4*)(tp + 4);
        u16 outv[8] = {f2b(a0.x), f2b(a0.y), f2b(a0.z), f2b(a0.w),
                       f2b(a1.x), f2b(a1.y), f2b(a1.z), f2b(a1.w)};
        *(uint4*)(tks + p * 72 + dg) = *(uint4*)outv;
    }
    __syncthreads();

    int lane = tid & 63, wave = tid >> 6;
    int r16 = lane & 15, quad = lane >> 4;
    int mb = (wave >> 1) * 64, nb = (wave & 1) * 64;

    f32x4 acc[4][4];
#pragma unroll
    for (int mt = 0; mt < 4; mt++)
#pragma unroll
        for (int nt = 0; nt < 4; nt++) acc[mt][nt] = (f32x4){0.f, 0.f, 0.f, 0.f};

#pragma unroll
    for (int k0 = 0; k0 < 64; k0 += 32) {
        bf16x8 af[4], bfr[4];
#pragma unroll
        for (int mt = 0; mt < 4; mt++)
            af[mt] = *(const bf16x8*)(qs + (mb + mt * 16 + r16) * 72 + k0 + quad * 8);
#pragma unroll
        for (int nt = 0; nt < 4; nt++)
            bfr[nt] = *(const bf16x8*)(tks + (nb + nt * 16 + r16) * 72 + k0 + quad * 8);
#pragma unroll
        for (int mt = 0; mt < 4; mt++)
#pragma unroll
            for (int nt = 0; nt < 4; nt++)
                acc[mt][nt] = __builtin_amdgcn_mfma_f32_16x16x32_bf16(af[mt], bfr[nt], acc[mt][nt], 0, 0, 0);
    }

    size_t basebh = ((size_t)(b * HH + h)) * (TT * PP);
#pragma unroll
    for (int mt = 0; mt < 4; mt++)
#pragma unroll
        for (int nt = 0; nt < 4; nt++)
#pragma unroll
            for (int rg = 0; rg < 4; rg++) {
                int tp = t0 + mb + mt * 16 + quad * 4 + rg;
                int ppx = nb + nt * 16 + r16;
                int o = tp * PP + (tp >> 3) + 1 - PP + ppx;
                if (o >= 0) tsb[basebh + o] = f2b(acc[mt][nt][rg]);
            }
    if (blockIdx.x == 0 && tid < 127) {
        int tp = tid + 1;
        tsb[basebh + 1025 * tp - PP] = 0;
    }
}

// ---------------------------------------------------------------------------
// k_vt: V transpose. vt[b][kvh][d][s] = kv[b*T+s][256 + kvh*64 + d]  (bf16)
// ---------------------------------------------------------------------------
__global__ __launch_bounds__(256) void k_vt(const u16* __restrict__ kvb,
                                            u16* __restrict__ vt) {
    int k = blockIdx.x * 256 + threadIdx.x;  // < 524288
    int s = k & 1023, d = (k >> 10) & 63, kvh = (k >> 16) & 3, b = k >> 18;
    vt[k] = kvb[((size_t)(b * TT + s)) * (2 * EKVV) + EKVV + kvh * 64 + d];
}

// ---------------------------------------------------------------------------
// k_att4: big-tile MFMA flash attention. One block per (b, h, 64-row group).
// grid (16, 16, 2) = 512 blocks. Per s-chunk of 128: QK MFMA (16 real rows
// per wave, scores in registers), in-register online softmax (shfl over the
// 16-lane column group), P via per-wave-private LDS (aliased on Kst), PV MFMA
// accumulated across chunks with per-row alpha rescale.
// Fragment maps (verified): A[m=lane&15][k=quad*8+j], B[k=quad*8+j][n=lane&15],
// C[row=quad*4+rg][col=lane&15].
// ---------------------------------------------------------------------------
__global__ __launch_bounds__(256) void k_att4(const u16* __restrict__ qb,
                                              const u16* __restrict__ kvb,
                                              const u16* __restrict__ vt,
                                              const u16* __restrict__ tsb,
                                              const float* __restrict__ ckb,
                                              const float* __restrict__ bias,
                                              u16* __restrict__ A2) {
    __shared__ __align__(16) char smem[54016];
    u16*   qg   = (u16*)(smem);              // [64][72] bf16 (q + gb)
    u16*   KP   = (u16*)(smem + 9216);       // Kst [128][72] | P [64][136]
    u16*   Vst  = (u16*)(smem + 27648);      // [64][138] bf16 (d-major)
    float* tsA  = (float*)(smem + 45312);    // [64][17] chunk time-shift
    float* csA  = (float*)(smem + 49664);    // [64][8] chan scores
    float* cks  = (float*)(smem + 51712);    // [8][64] ck rows
    float* cbmg = (float*)(smem + 53760);    // [64] cb - gb

    int tid = threadIdx.x;
    int lane = tid & 63, wave = tid >> 6;
    int r16 = lane & 15, quad = lane >> 4;
    int g = blockIdx.x, h = blockIdx.y, b = blockIdx.z;
    int kvh = h >> 2;
    int t0 = g * 64;

    // ---- stage qg = bf16(q + gb) ----
#pragma unroll
    for (int i = 0; i < 2; i++) {
        int idx = tid + i * 256;             // 512 = 64 rows x 8 groups
        int row = idx >> 3, dg = (idx & 7) << 3;
        uint4 u = *(const uint4*)(qb + ((size_t)(b * TT + t0 + row)) * EE + h * 64 + dg);
        u16 tmp[8]; *(uint4*)tmp = u;
        u16 o[8];
#pragma unroll
        for (int j = 0; j < 8; j++) o[j] = f2b(b2f(tmp[j]) + bias[kvh * 64 + dg + j]);
        *(uint4*)(qg + row * 72 + dg) = *(uint4*)o;
    }
    if (tid < 64) cbmg[tid] = bias[2 * EKVV + kvh * 64 + tid] - bias[kvh * 64 + tid];
#pragma unroll
    for (int i = 0; i < 2; i++) {
        int idx = tid + i * 256;             // 512 = 8 c x 64 d
        cks[idx] = ckb[(idx >> 6) * EKVV + kvh * 64 + (idx & 63)];
    }
    __syncthreads();

    // ---- csA[row][c] = (q + cb) . ck[7-|row%8-c|]  (from qg + (cb-gb)) ----
    {
        int row = tid >> 2, cA = (tid & 3) << 1;
        int rm8 = row & 7;
        int d0 = rm8 - cA;       if (d0 < 0) d0 = -d0;
        int d1 = rm8 - (cA + 1); if (d1 < 0) d1 = -d1;
        const float* k0p = cks + (7 - d0) * 64;
        const float* k1p = cks + (7 - d1) * 64;
        float a0 = 0.f, a1 = 0.f;
#pragma unroll 8
        for (int d = 0; d < 64; d++) {
            float qv = b2f(qg[row * 72 + d]) + cbmg[d];
            a0 += qv * k0p[d];
            a1 += qv * k1p[d];
        }
        csA[row * 8 + cA] = a0;
        csA[row * 8 + cA + 1] = a1;
    }

    // ---- per-wave A fragments (wave owns rows wave*16..+15) ----
    bf16x8 aq0 = *(const bf16x8*)(qg + (wave * 16 + r16) * 72 + quad * 8);
    bf16x8 aq1 = *(const bf16x8*)(qg + (wave * 16 + r16) * 72 + 32 + quad * 8);

    float m[4], l[4];
    f32x4 accv[4];
#pragma unroll
    for (int rg = 0; rg < 4; rg++) { m[rg] = -1.0e30f; l[rg] = 0.f; }
#pragma unroll
    for (int nt = 0; nt < 4; nt++) accv[nt] = (f32x4){0.f, 0.f, 0.f, 0.f};

    int rowbase = wave * 16 + quad * 4;      // + rg = local row
    int nch = (g + 2) >> 1;                  // ceil(64*(g+1)/128)

    for (int ci = 0; ci < nch; ci++) {
        int c0 = ci * 128;
        bool needK = (g == 15) || (c0 + 128 > g * 64 - 80);
        __syncthreads();   // prev-iteration Vst/tsA/P readers done
        // stage V chunk (pre-transposed global -> direct b128 copies)
        {
            const u16* vsrc = vt + ((size_t)(b * KVHH + kvh)) * DD * TT + c0;
#pragma unroll
            for (int i = 0; i < 4; i++) {
                int idx = tid + i * 256;     // 1024 = 64 d x 16 sg
                int d = idx >> 4, sg = (idx & 15) << 3;
                *(uint4*)(Vst + d * 138 + sg) = *(const uint4*)(vsrc + (size_t)d * TT + sg);
            }
        }
        // stage tsA chunk (bf16 -> fp32)
        if (tid < 128) {
            int row = tid >> 1, half = (tid & 1) << 3;
            const u16* tp = tsb + ((size_t)(b * HH + h)) * (TT * PP)
                          + (size_t)(t0 + row) * PP + (c0 >> 3) + half;
            uint4 u = *(const uint4*)tp;
            u16 tmp[8]; *(uint4*)tmp = u;
#pragma unroll
            for (int j = 0; j < 8; j++) tsA[row * 17 + half + j] = b2f(tmp[j]);
        }
        // stage K chunk if needed
        if (needK) {
#pragma unroll
            for (int i = 0; i < 4; i++) {
                int idx = tid + i * 256;     // 1024 = 128 s x 8 groups
                int s = idx >> 3, dg = (idx & 7) << 3;
                *(uint4*)(KP + s * 72 + dg) =
                    *(const uint4*)(kvb + ((size_t)(b * TT + c0 + s)) * (2 * EKVV) + kvh * 64 + dg);
            }
        }
        __syncthreads();

        // QK MFMA: 8 n-tiles x 2 k-steps
        f32x4 sc[8];
        if (needK) {
#pragma unroll
            for (int nt = 0; nt < 8; nt++) {
                const u16* kp = KP + (nt * 16 + r16) * 72 + quad * 8;
                bf16x8 b0 = *(const bf16x8*)(kp);
                bf16x8 b1 = *(const bf16x8*)(kp + 32);
                f32x4 a = {0.f, 0.f, 0.f, 0.f};
                a = __builtin_amdgcn_mfma_f32_16x16x32_bf16(aq0, b0, a, 0, 0, 0);
                a = __builtin_amdgcn_mfma_f32_16x16x32_bf16(aq1, b1, a, 0, 0, 0);
                sc[nt] = a;
            }
        } else {
#pragma unroll
            for (int nt = 0; nt < 8; nt++) sc[nt] = (f32x4){0.f, 0.f, 0.f, 0.f};
        }

        // scores: (win?dot:0 + ts + cs)/8, causal mask
#pragma unroll
        for (int nt = 0; nt < 8; nt++) {
            int s = c0 + nt * 16 + r16;
            int spi = s >> 3;
#pragma unroll
            for (int rg = 0; rg < 4; rg++) {
                int rloc = rowbase + rg;
                int rpi = (t0 + rloc) >> 3;
                float ts = tsA[rloc * 17 + 2 * nt + (r16 >> 3)];
                float cs = csA[rloc * 8 + (r16 & 7)];
                bool win = (rpi == 127) || (rpi - spi <= 10);
                float scv = ((win ? sc[nt][rg] : 0.f) + ts + cs) * 0.125f;
                sc[nt][rg] = (spi <= rpi) ? scv : -1.0e30f;
            }
        }

        // online softmax in registers (reduce over the 16-lane col group)
        float cm[4], alpha[4], psum[4];
#pragma unroll
        for (int rg = 0; rg < 4; rg++) {
            float v = sc[0][rg];
#pragma unroll
            for (int nt = 1; nt < 8; nt++) v = fmaxf(v, sc[nt][rg]);
#pragma unroll
            for (int off = 1; off < 16; off <<= 1) v = fmaxf(v, __shfl_xor(v, off));
            float mn = fmaxf(m[rg], v);
            alpha[rg] = __expf(m[rg] - mn);
            m[rg] = mn;
            cm[rg] = mn;
        }
#pragma unroll
        for (int rg = 0; rg < 4; rg++) psum[rg] = 0.f;
#pragma unroll
        for (int nt = 0; nt < 8; nt++)
#pragma unroll
            for (int rg = 0; rg < 4; rg++) {
                float e = __expf(sc[nt][rg] - cm[rg]);
                sc[nt][rg] = e;
                psum[rg] += e;
            }
#pragma unroll
        for (int rg = 0; rg < 4; rg++) {
#pragma unroll
            for (int off = 1; off < 16; off <<= 1) psum[rg] += __shfl_xor(psum[rg], off);
            l[rg] = l[rg] * alpha[rg] + psum[rg];
        }
        // rescale O accumulator
#pragma unroll
        for (int nt = 0; nt < 4; nt++)
#pragma unroll
            for (int rg = 0; rg < 4; rg++) accv[nt][rg] *= alpha[rg];

        // write P (bf16) -- aliases Kst, so sync all QK readers first
        __syncthreads();
#pragma unroll
        for (int nt = 0; nt < 8; nt++)
#pragma unroll
            for (int rg = 0; rg < 4; rg++)
                KP[(rowbase + rg) * 136 + nt * 16 + r16] = f2b(sc[nt][rg]);
        __syncthreads();

        // PV MFMA: 4 k-steps x 4 d-tiles
#pragma unroll
        for (int ks = 0; ks < 4; ks++) {
            bf16x8 ap = *(const bf16x8*)(KP + (wave * 16 + r16) * 136 + ks * 32 + quad * 8);
#pragma unroll
            for (int nt = 0; nt < 4; nt++) {
                bf16x8 bv = *(const bf16x8*)(Vst + (nt * 16 + r16) * 138 + ks * 32 + quad * 8);
                accv[nt] = __builtin_amdgcn_mfma_f32_16x16x32_bf16(ap, bv, accv[nt], 0, 0, 0);
            }
        }
    }

    // epilogue: O / l -> A2
#pragma unroll
    for (int nt = 0; nt < 4; nt++)
#pragma unroll
        for (int rg = 0; rg < 4; rg++) {
            int rt = t0 + rowbase + rg;
            A2[((size_t)(b * TT + rt)) * EE + h * 64 + nt * 16 + r16] =
                f2b(accv[nt][rg] / l[rg]);
        }
}

extern "C" void kernel_launch(void* const* d_in, const int* in_sizes, int n_in,
                              void* d_out, int out_size, void* d_ws, size_t ws_size,
                              hipStream_t stream) {
    const float* hidden = (const float*)d_in[0];
    const float* pos    = (const float*)d_in[1];
    const float* chan   = (const float*)d_in[2];
    const float* Wq     = (const float*)d_in[3];
    const float* Wkv    = (const float*)d_in[4];
    const float* Wpos   = (const float*)d_in[5];
    const float* Wchan  = (const float*)d_in[6];
    const float* Wproj  = (const float*)d_in[7];
    const float* bias   = (const float*)d_in[8];

    // workspace carve: ~19.3 MB total
    u16* qb    = (u16*)d_ws;               // 2,097,152 u16 (4 MB)
    u16* kvb   = qb + 2097152;             // 1,048,576 u16 (2 MB)
    u16* tsb   = kvb + 1048576;            // 4,194,304 u16 (8 MB)
    u16* A2    = tsb + 4194304;            // 2,097,152 u16 (4 MB)
    u16* vt    = A2 + 2097152;             //   524,288 u16 (1 MB)
    float* tkb = (float*)(vt + 524288);    //    32,768 f32 (128 KB)
    float* ckb = tkb + 32768;              //     2,048 f32 (8 KB)

    dim3 blk(256);
    // small projections (fp32 outputs, VALU)
    gemm_ff<<<dim3(4, 2), blk, 0, stream>>>(pos,  Wpos,  tkb, nullptr, 128, 256, 1024);
    gemm_ff<<<dim3(4, 1), blk, 0, stream>>>(chan, Wchan, ckb, nullptr, 8,   256, 1024);
    // fused q/kv projection via MFMA
    mgemm_qkv<<<dim3(12, 16), blk, 0, stream>>>(hidden, Wq, Wkv, qb, kvb);
    // V transpose
    k_vt<<<2048, blk, 0, stream>>>(kvb, vt);
    // MFMA time_att with fused rel-shift scatter -> tsb (bf16)
    mk_ta<<<dim3(8, 16, 2), blk, 0, stream>>>(qb, tkb, bias, tsb);
    // big-tile MFMA flash attention -> A2 (bf16)
    k_att4<<<dim3(16, 16, 2), blk, 0, stream>>>(qb, kvb, vt, tsb, ckb, bias, A2);
    // output projection via MFMA -> fp32 d_out
    mgemm_proj<<<dim3(8, 16), blk, 0, stream>>>(A2, Wproj, (float*)d_out);
}

// Round 12
// 283.766 us; speedup vs baseline: 3.8537x; 1.3531x over previous
//
#include <hip/hip_runtime.h>
#include <hip/hip_bf16.h>

#define BB 2
#define PP 128
#define CC 8
#define EE 1024
#define HH 16
#define KVHH 4
#define DD 64
#define TT 1024
#define EKVV 256

typedef unsigned short u16;
typedef unsigned int u32;
typedef __attribute__((ext_vector_type(8))) short bf16x8;
typedef __attribute__((ext_vector_type(4))) float f32x4;

__device__ __forceinline__ float b2f(u16 u) {
    u32 x = ((u32)u) << 16;
    return __uint_as_float(x);
}
__device__ __forceinline__ u16 f2b(float f) {
    u32 x = __float_as_uint(f);
    u32 r = (x + 0x7FFFu + ((x >> 16) & 1u)) >> 16;
    return (u16)r;
}

// ---------------------------------------------------------------------------
// sgemm_sk: split-K GEMM for the two tiny projections (pos 128x256, chan
// 8x256; K=1024). Tile 64x64, K-split 8 (128 K per block, 8 BK=16 iters).
// Partial sums atomicAdd'ed into pre-zeroed fp32 outputs.
// grid.x: 0..7 pos tiles (2m x 4n), 8..11 chan tiles (1m x 4n); grid.y: ksplit.
// ---------------------------------------------------------------------------
__global__ __launch_bounds__(256) void sgemm_sk(const float* __restrict__ pos,
                                                const float* __restrict__ Wpos,
                                                const float* __restrict__ chan,
                                                const float* __restrict__ Wchan,
                                                float* __restrict__ tkb,
                                                float* __restrict__ ckb) {
    __shared__ float As[16][68];
    __shared__ float Bs[16][68];
    int tile = blockIdx.x;
    const float* A; const float* B; float* C; int M, m0, n0;
    if (tile < 8) { A = pos;  B = Wpos;  C = tkb; M = 128; m0 = (tile >> 2) * 64; n0 = (tile & 3) * 64; }
    else          { A = chan; B = Wchan; C = ckb; M = 8;   m0 = 0;               n0 = (tile - 8) * 64; }
    int kbase = blockIdx.y * 128;

    int tid = threadIdx.x;
    int tx = tid & 15, ty = tid >> 4;
    float acc[4][4];
#pragma unroll
    for (int r = 0; r < 4; r++)
#pragma unroll
        for (int c = 0; c < 4; c++) acc[r][c] = 0.f;

    int am = tid >> 2, ak = (tid & 3) << 2;
    int bk = tid >> 4, bn = (tid & 15) << 2;

    for (int k0 = kbase; k0 < kbase + 128; k0 += 16) {
        int row = m0 + am;
        float4 av;
        if (row < M) av = *reinterpret_cast<const float4*>(A + (size_t)row * 1024 + k0 + ak);
        else av = make_float4(0.f, 0.f, 0.f, 0.f);
        As[ak + 0][am] = av.x;
        As[ak + 1][am] = av.y;
        As[ak + 2][am] = av.z;
        As[ak + 3][am] = av.w;
        float4 bv = *reinterpret_cast<const float4*>(B + (size_t)(k0 + bk) * 256 + n0 + bn);
        Bs[bk][bn + 0] = bv.x;
        Bs[bk][bn + 1] = bv.y;
        Bs[bk][bn + 2] = bv.z;
        Bs[bk][bn + 3] = bv.w;
        __syncthreads();
#pragma unroll
        for (int kk = 0; kk < 16; kk++) {
            float4 a4 = *reinterpret_cast<const float4*>(&As[kk][ty << 2]);
            float4 b4 = *reinterpret_cast<const float4*>(&Bs[kk][tx << 2]);
            acc[0][0] += a4.x * b4.x; acc[0][1] += a4.x * b4.y; acc[0][2] += a4.x * b4.z; acc[0][3] += a4.x * b4.w;
            acc[1][0] += a4.y * b4.x; acc[1][1] += a4.y * b4.y; acc[1][2] += a4.y * b4.z; acc[1][3] += a4.y * b4.w;
            acc[2][0] += a4.z * b4.x; acc[2][1] += a4.z * b4.y; acc[2][2] += a4.z * b4.z; acc[2][3] += a4.z * b4.w;
            acc[3][0] += a4.w * b4.x; acc[3][1] += a4.w * b4.y; acc[3][2] += a4.w * b4.z; acc[3][3] += a4.w * b4.w;
        }
        __syncthreads();
    }
#pragma unroll
    for (int r = 0; r < 4; r++) {
        int row = m0 + (ty << 2) + r;
        if (row < M) {
#pragma unroll
            for (int c = 0; c < 4; c++) {
                int col = n0 + (tx << 2) + c;
                atomicAdd(&C[(size_t)row * 256 + col], acc[r][c]);
            }
        }
    }
}

// ---------------------------------------------------------------------------
// MFMA GEMM, fused q/kv projection (unchanged).
// ---------------------------------------------------------------------------
__global__ __launch_bounds__(256) void mgemm_qkv(const float* __restrict__ A,
                                                 const float* __restrict__ Wq,
                                                 const float* __restrict__ Wkv,
                                                 u16* __restrict__ qout,
                                                 u16* __restrict__ kvout) {
    __shared__ __align__(16) u16 As[128 * 40];
    __shared__ __align__(16) u16 Bs[128 * 40];
    int tid = threadIdx.x;
    int ntile = blockIdx.x;
    int m0 = blockIdx.y * 128;
    const float* B;
    u16* Cout;
    int BN, n0;
    if (ntile < 8) { B = Wq;  Cout = qout;  BN = 1024; n0 = ntile * 128; }
    else           { B = Wkv; Cout = kvout; BN = 512;  n0 = (ntile - 8) * 128; }

    int lane = tid & 63, wave = tid >> 6;
    int r16 = lane & 15, quad = lane >> 4;
    int mb = (wave >> 1) * 64, nb = (wave & 1) * 64;

    f32x4 acc[4][4];
#pragma unroll
    for (int mt = 0; mt < 4; mt++)
#pragma unroll
        for (int nt = 0; nt < 4; nt++) acc[mt][nt] = (f32x4){0.f, 0.f, 0.f, 0.f};

    for (int k0 = 0; k0 < 1024; k0 += 32) {
        __syncthreads();
#pragma unroll
        for (int it = 0; it < 2; it++) {
            int idx = tid + it * 256;
            int row = idx >> 2, kg = (idx & 3) << 3;
            const float* ap = A + (size_t)(m0 + row) * 1024 + k0 + kg;
            float4 a0 = *(const float4*)(ap);
            float4 a1 = *(const float4*)(ap + 4);
            u16 tmp[8] = {f2b(a0.x), f2b(a0.y), f2b(a0.z), f2b(a0.w),
                          f2b(a1.x), f2b(a1.y), f2b(a1.z), f2b(a1.w)};
            *(uint4*)(As + row * 40 + kg) = *(uint4*)tmp;
        }
#pragma unroll
        for (int it = 0; it < 4; it++) {
            int idx = tid + it * 256;
            int krow = idx >> 5, ng = (idx & 31) << 2;
            float4 bv = *(const float4*)(B + (size_t)(k0 + krow) * BN + n0 + ng);
            Bs[(ng + 0) * 40 + krow] = f2b(bv.x);
            Bs[(ng + 1) * 40 + krow] = f2b(bv.y);
            Bs[(ng + 2) * 40 + krow] = f2b(bv.z);
            Bs[(ng + 3) * 40 + krow] = f2b(bv.w);
        }
        __syncthreads();
        bf16x8 af[4], bfr[4];
#pragma unroll
        for (int mt = 0; mt < 4; mt++)
            af[mt] = *(const bf16x8*)(As + (mb + mt * 16 + r16) * 40 + quad * 8);
#pragma unroll
        for (int nt = 0; nt < 4; nt++)
            bfr[nt] = *(const bf16x8*)(Bs + (nb + nt * 16 + r16) * 40 + quad * 8);
#pragma unroll
        for (int mt = 0; mt < 4; mt++)
#pragma unroll
            for (int nt = 0; nt < 4; nt++)
                acc[mt][nt] = __builtin_amdgcn_mfma_f32_16x16x32_bf16(af[mt], bfr[nt], acc[mt][nt], 0, 0, 0);
    }
#pragma unroll
    for (int mt = 0; mt < 4; mt++)
#pragma unroll
        for (int nt = 0; nt < 4; nt++)
#pragma unroll
            for (int rg = 0; rg < 4; rg++) {
                int row = m0 + mb + mt * 16 + quad * 4 + rg;
                int col = n0 + nb + nt * 16 + r16;
                Cout[(size_t)row * BN + col] = f2b(acc[mt][nt][rg]);
            }
}

// ---------------------------------------------------------------------------
// MFMA GEMM, output projection (unchanged).
// ---------------------------------------------------------------------------
__global__ __launch_bounds__(256) void mgemm_proj(const u16* __restrict__ A,
                                                  const float* __restrict__ B,
                                                  float* __restrict__ Cf) {
    __shared__ __align__(16) u16 As[128 * 40];
    __shared__ __align__(16) u16 Bs[128 * 40];
    int tid = threadIdx.x;
    int n0 = blockIdx.x * 128;
    int m0 = blockIdx.y * 128;

    int lane = tid & 63, wave = tid >> 6;
    int r16 = lane & 15, quad = lane >> 4;
    int mb = (wave >> 1) * 64, nb = (wave & 1) * 64;

    f32x4 acc[4][4];
#pragma unroll
    for (int mt = 0; mt < 4; mt++)
#pragma unroll
        for (int nt = 0; nt < 4; nt++) acc[mt][nt] = (f32x4){0.f, 0.f, 0.f, 0.f};

    for (int k0 = 0; k0 < 1024; k0 += 32) {
        __syncthreads();
#pragma unroll
        for (int it = 0; it < 2; it++) {
            int idx = tid + it * 256;
            int row = idx >> 2, kg = (idx & 3) << 3;
            *(uint4*)(As + row * 40 + kg) =
                *(const uint4*)(A + (size_t)(m0 + row) * 1024 + k0 + kg);
        }
#pragma unroll
        for (int it = 0; it < 4; it++) {
            int idx = tid + it * 256;
            int krow = idx >> 5, ng = (idx & 31) << 2;
            float4 bv = *(const float4*)(B + (size_t)(k0 + krow) * 1024 + n0 + ng);
            Bs[(ng + 0) * 40 + krow] = f2b(bv.x);
            Bs[(ng + 1) * 40 + krow] = f2b(bv.y);
            Bs[(ng + 2) * 40 + krow] = f2b(bv.z);
            Bs[(ng + 3) * 40 + krow] = f2b(bv.w);
        }
        __syncthreads();
        bf16x8 af[4], bfr[4];
#pragma unroll
        for (int mt = 0; mt < 4; mt++)
            af[mt] = *(const bf16x8*)(As + (mb + mt * 16 + r16) * 40 + quad * 8);
#pragma unroll
        for (int nt = 0; nt < 4; nt++)
            bfr[nt] = *(const bf16x8*)(Bs + (nb + nt * 16 + r16) * 40 + quad * 8);
#pragma unroll
        for (int mt = 0; mt < 4; mt++)
#pragma unroll
            for (int nt = 0; nt < 4; nt++)
                acc[mt][nt] = __builtin_amdgcn_mfma_f32_16x16x32_bf16(af[mt], bfr[nt], acc[mt][nt], 0, 0, 0);
    }
#pragma unroll
    for (int mt = 0; mt < 4; mt++)
#pragma unroll
        for (int nt = 0; nt < 4; nt++)
#pragma unroll
            for (int rg = 0; rg < 4; rg++) {
                int row = m0 + mb + mt * 16 + quad * 4 + rg;
                int col = n0 + nb + nt * 16 + r16;
                Cf[(size_t)row * 1024 + col] = acc[mt][nt][rg];
            }
}

// ---------------------------------------------------------------------------
// mk_ta: MFMA time_att with fused rel-shift scatter (unchanged).
// ---------------------------------------------------------------------------
__global__ __launch_bounds__(256) void mk_ta(const u16* __restrict__ qb,
                                             const float* __restrict__ tkb,
                                             const float* __restrict__ bias,
                                             u16* __restrict__ tsb) {
    __shared__ __align__(16) u16 qs[128 * 72];
    __shared__ __align__(16) u16 tks[128 * 72];
    int tid = threadIdx.x;
    int t0 = blockIdx.x * 128;
    int h = blockIdx.y, b = blockIdx.z;
    int kvh = h >> 2;

#pragma unroll
    for (int it = 0; it < 4; it++) {
        int idx = tid + it * 256;
        int r = idx >> 3, dg = (idx & 7) << 3;
        uint4 u = *(const uint4*)(qb + ((size_t)(b * TT + t0 + r)) * EE + h * 64 + dg);
        u16 tmp[8]; *(uint4*)tmp = u;
        u16 outv[8];
#pragma unroll
        for (int j = 0; j < 8; j++) outv[j] = f2b(b2f(tmp[j]) + bias[EKVV + kvh * 64 + dg + j]);
        *(uint4*)(qs + r * 72 + dg) = *(uint4*)outv;
    }
#pragma unroll
    for (int it = 0; it < 4; it++) {
        int idx = tid + it * 256;
        int p = idx >> 3, dg = (idx & 7) << 3;
        const float* tp = tkb + p * EKVV + kvh * 64 + dg;
        float4 a0 = *(const float4*)(tp);
        float4 a1 = *(const float4*)(tp + 4);
        u16 outv[8] = {f2b(a0.x), f2b(a0.y), f2b(a0.z), f2b(a0.w),
                       f2b(a1.x), f2b(a1.y), f2b(a1.z), f2b(a1.w)};
        *(uint4*)(tks + p * 72 + dg) = *(uint4*)outv;
    }
    __syncthreads();

    int lane = tid & 63, wave = tid >> 6;
    int r16 = lane & 15, quad = lane >> 4;
    int mb = (wave >> 1) * 64, nb = (wave & 1) * 64;

    f32x4 acc[4][4];
#pragma unroll
    for (int mt = 0; mt < 4; mt++)
#pragma unroll
        for (int nt = 0; nt < 4; nt++) acc[mt][nt] = (f32x4){0.f, 0.f, 0.f, 0.f};

#pragma unroll
    for (int k0 = 0; k0 < 64; k0 += 32) {
        bf16x8 af[4], bfr[4];
#pragma unroll
        for (int mt = 0; mt < 4; mt++)
            af[mt] = *(const bf16x8*)(qs + (mb + mt * 16 + r16) * 72 + k0 + quad * 8);
#pragma unroll
        for (int nt = 0; nt < 4; nt++)
            bfr[nt] = *(const bf16x8*)(tks + (nb + nt * 16 + r16) * 72 + k0 + quad * 8);
#pragma unroll
        for (int mt = 0; mt < 4; mt++)
#pragma unroll
            for (int nt = 0; nt < 4; nt++)
                acc[mt][nt] = __builtin_amdgcn_mfma_f32_16x16x32_bf16(af[mt], bfr[nt], acc[mt][nt], 0, 0, 0);
    }

    size_t basebh = ((size_t)(b * HH + h)) * (TT * PP);
#pragma unroll
    for (int mt = 0; mt < 4; mt++)
#pragma unroll
        for (int nt = 0; nt < 4; nt++)
#pragma unroll
            for (int rg = 0; rg < 4; rg++) {
                int tp = t0 + mb + mt * 16 + quad * 4 + rg;
                int ppx = nb + nt * 16 + r16;
                int o = tp * PP + (tp >> 3) + 1 - PP + ppx;
                if (o >= 0) tsb[basebh + o] = f2b(acc[mt][nt][rg]);
            }
    if (blockIdx.x == 0 && tid < 127) {
        int tp = tid + 1;
        tsb[basebh + 1025 * tp - PP] = 0;
    }
}

// ---------------------------------------------------------------------------
// k_vt: V transpose. vt[b][kvh][d][s] = kv[b*T+s][256 + kvh*64 + d]  (bf16)
// ---------------------------------------------------------------------------
__global__ __launch_bounds__(256) void k_vt(const u16* __restrict__ kvb,
                                            u16* __restrict__ vt) {
    int k = blockIdx.x * 256 + threadIdx.x;  // < 524288
    int s = k & 1023, d = (k >> 10) & 63, kvh = (k >> 16) & 3, b = k >> 18;
    vt[k] = kvb[((size_t)(b * TT + s)) * (2 * EKVV) + EKVV + kvh * 64 + d];
}

// ---------------------------------------------------------------------------
// k_att4: big-tile MFMA flash attention (unchanged from round 11).
// ---------------------------------------------------------------------------
__global__ __launch_bounds__(256) void k_att4(const u16* __restrict__ qb,
                                              const u16* __restrict__ kvb,
                                              const u16* __restrict__ vt,
                                              const u16* __restrict__ tsb,
                                              const float* __restrict__ ckb,
                                              const float* __restrict__ bias,
                                              u16* __restrict__ A2) {
    __shared__ __align__(16) char smem[54016];
    u16*   qg   = (u16*)(smem);              // [64][72] bf16 (q + gb)
    u16*   KP   = (u16*)(smem + 9216);       // Kst [128][72] | P [64][136]
    u16*   Vst  = (u16*)(smem + 27648);      // [64][138] bf16 (d-major)
    float* tsA  = (float*)(smem + 45312);    // [64][17] chunk time-shift
    float* csA  = (float*)(smem + 49664);    // [64][8] chan scores
    float* cks  = (float*)(smem + 51712);    // [8][64] ck rows
    float* cbmg = (float*)(smem + 53760);    // [64] cb - gb

    int tid = threadIdx.x;
    int lane = tid & 63, wave = tid >> 6;
    int r16 = lane & 15, quad = lane >> 4;
    int g = blockIdx.x, h = blockIdx.y, b = blockIdx.z;
    int kvh = h >> 2;
    int t0 = g * 64;

#pragma unroll
    for (int i = 0; i < 2; i++) {
        int idx = tid + i * 256;
        int row = idx >> 3, dg = (idx & 7) << 3;
        uint4 u = *(const uint4*)(qb + ((size_t)(b * TT + t0 + row)) * EE + h * 64 + dg);
        u16 tmp[8]; *(uint4*)tmp = u;
        u16 o[8];
#pragma unroll
        for (int j = 0; j < 8; j++) o[j] = f2b(b2f(tmp[j]) + bias[kvh * 64 + dg + j]);
        *(uint4*)(qg + row * 72 + dg) = *(uint4*)o;
    }
    if (tid < 64) cbmg[tid] = bias[2 * EKVV + kvh * 64 + tid] - bias[kvh * 64 + tid];
#pragma unroll
    for (int i = 0; i < 2; i++) {
        int idx = tid + i * 256;
        cks[idx] = ckb[(idx >> 6) * EKVV + kvh * 64 + (idx & 63)];
    }
    __syncthreads();

    {
        int row = tid >> 2, cA = (tid & 3) << 1;
        int rm8 = row & 7;
        int d0 = rm8 - cA;       if (d0 < 0) d0 = -d0;
        int d1 = rm8 - (cA + 1); if (d1 < 0) d1 = -d1;
        const float* k0p = cks + (7 - d0) * 64;
        const float* k1p = cks + (7 - d1) * 64;
        float a0 = 0.f, a1 = 0.f;
#pragma unroll 8
        for (int d = 0; d < 64; d++) {
            float qv = b2f(qg[row * 72 + d]) + cbmg[d];
            a0 += qv * k0p[d];
            a1 += qv * k1p[d];
        }
        csA[row * 8 + cA] = a0;
        csA[row * 8 + cA + 1] = a1;
    }

    bf16x8 aq0 = *(const bf16x8*)(qg + (wave * 16 + r16) * 72 + quad * 8);
    bf16x8 aq1 = *(const bf16x8*)(qg + (wave * 16 + r16) * 72 + 32 + quad * 8);

    float m[4], l[4];
    f32x4 accv[4];
#pragma unroll
    for (int rg = 0; rg < 4; rg++) { m[rg] = -1.0e30f; l[rg] = 0.f; }
#pragma unroll
    for (int nt = 0; nt < 4; nt++) accv[nt] = (f32x4){0.f, 0.f, 0.f, 0.f};

    int rowbase = wave * 16 + quad * 4;
    int nch = (g + 2) >> 1;

    for (int ci = 0; ci < nch; ci++) {
        int c0 = ci * 128;
        bool needK = (g == 15) || (c0 + 128 > g * 64 - 80);
        __syncthreads();
        {
            const u16* vsrc = vt + ((size_t)(b * KVHH + kvh)) * DD * TT + c0;
#pragma unroll
            for (int i = 0; i < 4; i++) {
                int idx = tid + i * 256;
                int d = idx >> 4, sg = (idx & 15) << 3;
                *(uint4*)(Vst + d * 138 + sg) = *(const uint4*)(vsrc + (size_t)d * TT + sg);
            }
        }
        if (tid < 128) {
            int row = tid >> 1, half = (tid & 1) << 3;
            const u16* tp = tsb + ((size_t)(b * HH + h)) * (TT * PP)
                          + (size_t)(t0 + row) * PP + (c0 >> 3) + half;
            uint4 u = *(const uint4*)tp;
            u16 tmp[8]; *(uint4*)tmp = u;
#pragma unroll
            for (int j = 0; j < 8; j++) tsA[row * 17 + half + j] = b2f(tmp[j]);
        }
        if (needK) {
#pragma unroll
            for (int i = 0; i < 4; i++) {
                int idx = tid + i * 256;
                int s = idx >> 3, dg = (idx & 7) << 3;
                *(uint4*)(KP + s * 72 + dg) =
                    *(const uint4*)(kvb + ((size_t)(b * TT + c0 + s)) * (2 * EKVV) + kvh * 64 + dg);
            }
        }
        __syncthreads();

        f32x4 sc[8];
        if (needK) {
#pragma unroll
            for (int nt = 0; nt < 8; nt++) {
                const u16* kp = KP + (nt * 16 + r16) * 72 + quad * 8;
                bf16x8 b0 = *(const bf16x8*)(kp);
                bf16x8 b1 = *(const bf16x8*)(kp + 32);
                f32x4 a = {0.f, 0.f, 0.f, 0.f};
                a = __builtin_amdgcn_mfma_f32_16x16x32_bf16(aq0, b0, a, 0, 0, 0);
                a = __builtin_amdgcn_mfma_f32_16x16x32_bf16(aq1, b1, a, 0, 0, 0);
                sc[nt] = a;
            }
        } else {
#pragma unroll
            for (int nt = 0; nt < 8; nt++) sc[nt] = (f32x4){0.f, 0.f, 0.f, 0.f};
        }

#pragma unroll
        for (int nt = 0; nt < 8; nt++) {
            int s = c0 + nt * 16 + r16;
            int spi = s >> 3;
#pragma unroll
            for (int rg = 0; rg < 4; rg++) {
                int rloc = rowbase + rg;
                int rpi = (t0 + rloc) >> 3;
                float ts = tsA[rloc * 17 + 2 * nt + (r16 >> 3)];
                float cs = csA[rloc * 8 + (r16 & 7)];
                bool win = (rpi == 127) || (rpi - spi <= 10);
                float scv = ((win ? sc[nt][rg] : 0.f) + ts + cs) * 0.125f;
                sc[nt][rg] = (spi <= rpi) ? scv : -1.0e30f;
            }
        }

        float cm[4], alpha[4], psum[4];
#pragma unroll
        for (int rg = 0; rg < 4; rg++) {
            float v = sc[0][rg];
#pragma unroll
            for (int nt = 1; nt < 8; nt++) v = fmaxf(v, sc[nt][rg]);
#pragma unroll
            for (int off = 1; off < 16; off <<= 1) v = fmaxf(v, __shfl_xor(v, off));
            float mn = fmaxf(m[rg], v);
            alpha[rg] = __expf(m[rg] - mn);
            m[rg] = mn;
            cm[rg] = mn;
        }
#pragma unroll
        for (int rg = 0; rg < 4; rg++) psum[rg] = 0.f;
#pragma unroll
        for (int nt = 0; nt < 8; nt++)
#pragma unroll
            for (int rg = 0; rg < 4; rg++) {
                float e = __expf(sc[nt][rg] - cm[rg]);
                sc[nt][rg] = e;
                psum[rg] += e;
            }
#pragma unroll
        for (int rg = 0; rg < 4; rg++) {
#pragma unroll
            for (int off = 1; off < 16; off <<= 1) psum[rg] += __shfl_xor(psum[rg], off);
            l[rg] = l[rg] * alpha[rg] + psum[rg];
        }
#pragma unroll
        for (int nt = 0; nt < 4; nt++)
#pragma unroll
            for (int rg = 0; rg < 4; rg++) accv[nt][rg] *= alpha[rg];

        __syncthreads();
#pragma unroll
        for (int nt = 0; nt < 8; nt++)
#pragma unroll
            for (int rg = 0; rg < 4; rg++)
                KP[(rowbase + rg) * 136 + nt * 16 + r16] = f2b(sc[nt][rg]);
        __syncthreads();

#pragma unroll
        for (int ks = 0; ks < 4; ks++) {
            bf16x8 ap = *(const bf16x8*)(KP + (wave * 16 + r16) * 136 + ks * 32 + quad * 8);
#pragma unroll
            for (int nt = 0; nt < 4; nt++) {
                bf16x8 bv = *(const bf16x8*)(Vst + (nt * 16 + r16) * 138 + ks * 32 + quad * 8);
                accv[nt] = __builtin_amdgcn_mfma_f32_16x16x32_bf16(ap, bv, accv[nt], 0, 0, 0);
            }
        }
    }

#pragma unroll
    for (int nt = 0; nt < 4; nt++)
#pragma unroll
        for (int rg = 0; rg < 4; rg++) {
            int rt = t0 + rowbase + rg;
            A2[((size_t)(b * TT + rt)) * EE + h * 64 + nt * 16 + r16] =
                f2b(accv[nt][rg] / l[rg]);
        }
}

extern "C" void kernel_launch(void* const* d_in, const int* in_sizes, int n_in,
                              void* d_out, int out_size, void* d_ws, size_t ws_size,
                              hipStream_t stream) {
    const float* hidden = (const float*)d_in[0];
    const float* pos    = (const float*)d_in[1];
    const float* chan   = (const float*)d_in[2];
    const float* Wq     = (const float*)d_in[3];
    const float* Wkv    = (const float*)d_in[4];
    const float* Wpos   = (const float*)d_in[5];
    const float* Wchan  = (const float*)d_in[6];
    const float* Wproj  = (const float*)d_in[7];
    const float* bias   = (const float*)d_in[8];

    // workspace carve: ~19.3 MB total
    u16* qb    = (u16*)d_ws;               // 2,097,152 u16 (4 MB)
    u16* kvb   = qb + 2097152;             // 1,048,576 u16 (2 MB)
    u16* tsb   = kvb + 1048576;            // 4,194,304 u16 (8 MB)
    u16* A2    = tsb + 4194304;            // 2,097,152 u16 (4 MB)
    u16* vt    = A2 + 2097152;             //   524,288 u16 (1 MB)
    float* tkb = (float*)(vt + 524288);    //    32,768 f32 (128 KB)
    float* ckb = tkb + 32768;              //     2,048 f32 (8 KB)

    dim3 blk(256);
    // zero the split-K accumulation buffers (tkb,ckb contiguous)
    hipMemsetAsync(tkb, 0, (32768 + 2048) * sizeof(float), stream);
    // tiny projections via split-K (pos + chan in one dispatch)
    sgemm_sk<<<dim3(12, 8), blk, 0, stream>>>(pos, Wpos, chan, Wchan, tkb, ckb);
    // fused q/kv projection via MFMA
    mgemm_qkv<<<dim3(12, 16), blk, 0, stream>>>(hidden, Wq, Wkv, qb, kvb);
    // V transpose
    k_vt<<<2048, blk, 0, stream>>>(kvb, vt);
    // MFMA time_att with fused rel-shift scatter -> tsb (bf16)
    mk_ta<<<dim3(8, 16, 2), blk, 0, stream>>>(qb, tkb, bias, tsb);
    // big-tile MFMA flash attention -> A2 (bf16)
    k_att4<<<dim3(16, 16, 2), blk, 0, stream>>>(qb, kvb, vt, tsb, ckb, bias, A2);
    // output projection via MFMA -> fp32 d_out
    mgemm_proj<<<dim3(8, 16), blk, 0, stream>>>(A2, Wproj, (float*)d_out);
}